// Round 17
// baseline (589.387 us; speedup 1.0000x reference)
//
#include <hip/hip_runtime.h>
#include <hip/hip_bf16.h>

#define N_NODES 100000
#define N_EDGES 3200000
#define N_GRAPHS 256
#define NB_BUCKETS 196      // ceil(100000 / 512)
#define BSHIFT 9            // 512 nodes per bucket
#define NBLK 256            // blocks for hist/bin passes
#define SCAN_BLKS 49        // 50176 / 1024

// ---------------- workspace layout (bytes) ----------------
#define OFF_SUMS      0u            // float[256*64] pool sums (zeroed in hist)
#define OFF_CNTF      65536u        // float[256] pool counts (zeroed in hist)
#define ZERO_BYTES    66560u
#define OFF_HIST      66560u        // int[196*256] (bucket-major) per-(bucket,block) counts
#define OFF_BSUM      267264u       // int[64] scan block sums
#define OFF_ROWPTR    267776u       // int[N+1]
#define OFF_DINV      668160u       // float[N]
#define OFF_COL       1068544u      // int[E]
#define OFF_XS1       13868544u     // float[N*8]
#define OFF_BUFQ      20268544u     // float[N*64]  xs2, later z3
#define OFF_BUFR      45868544u     // float[N*64]  z2, later ys
#define OFF_BUFP      71468544u     // float[N*128] h2; ALIASED: packed[E] (dead before h2)
#define OFF_PAIRS     OFF_BUFP
// total ~122.7 MB (proven through R16)

// ---- P1: per-(bucket,block) histogram of dst. Also zeroes the pool
// accumulators (was a separate zero_kernel dispatch).
__global__ __launch_bounds__(256) void hist_kernel(const int* __restrict__ dst,
                                                   int* __restrict__ hist,
                                                   int* __restrict__ zbase,
                                                   int E, int epb) {
    __shared__ int h[NB_BUCKETS];
    int t = threadIdx.x, blk = blockIdx.x;
    int gid = blk * 256 + t;
    if (gid < (int)(ZERO_BYTES / 4)) zbase[gid] = 0;
    if (t < NB_BUCKETS) h[t] = 0;
    __syncthreads();
    int e0 = blk * epb, e1 = min(e0 + epb, E);
    for (int e = e0 + t; e < e1; e += 256)
        atomicAdd(&h[__builtin_nontemporal_load(&dst[e]) >> BSHIFT], 1);
    __syncthreads();
    if (t < NB_BUCKETS) hist[t * NBLK + blk] = h[t];
}

// ---- P2: block-local exclusive scan of hist[50176] + per-block sums.
__global__ __launch_bounds__(1024) void scanhA_kernel(int* __restrict__ hist,
                                                      int* __restrict__ bsum) {
    __shared__ int s[1024];
    int t = threadIdx.x;
    int i = blockIdx.x * 1024 + t;     // 49*1024 == 50176 exactly
    int v = hist[i];
    s[t] = v;
    __syncthreads();
    for (int off = 1; off < 1024; off <<= 1) {
        int add = (t >= off) ? s[t - off] : 0;
        __syncthreads();
        s[t] += add;
        __syncthreads();
    }
    hist[i] = s[t] - v;                // block-local exclusive
    if (t == 1023) bsum[blockIdx.x] = s[t];
}

// ---- P3: bin edges, PACKED (dl<<17 | src), local offset scan.
__global__ __launch_bounds__(256) void bin_kernel(const int* __restrict__ src,
                                                  const int* __restrict__ dst,
                                                  const int* __restrict__ hist,
                                                  const int* __restrict__ bsum,
                                                  int* __restrict__ packed, int E, int epb) {
    __shared__ int cur[NB_BUCKETS];
    __shared__ int boffL[SCAN_BLKS];
    int t = threadIdx.x, blk = blockIdx.x;
    if (t < 64) {
        int orig = (t < SCAN_BLKS) ? bsum[t] : 0;
        int v = orig;
        for (int off = 1; off < 64; off <<= 1) {
            int up = __shfl_up(v, off);
            if (t >= off) v += up;
        }
        if (t < SCAN_BLKS) boffL[t] = v - orig;   // exclusive
    }
    __syncthreads();
    if (t < NB_BUCKETS) {
        int i = t * NBLK + blk;
        cur[t] = hist[i] + boffL[i >> 10];
    }
    __syncthreads();
    int e0 = blk * epb, e1 = min(e0 + epb, E);
    for (int e = e0 + t; e < e1; e += 256) {
        int d = __builtin_nontemporal_load(&dst[e]);
        int sv = __builtin_nontemporal_load(&src[e]);
        int pos = atomicAdd(&cur[d >> BSHIFT], 1);
        packed[pos] = ((d & 511) << 17) | sv;
    }
}

// ---- P4: per-bucket CSR finalize (row_ptr, dinv, col) + xs1 = dinv*x.
__global__ __launch_bounds__(512) void csr_kernel(const int* __restrict__ packed,
                                                  const int* __restrict__ hist,
                                                  const int* __restrict__ bsum,
                                                  const float* __restrict__ x,
                                                  int* __restrict__ row_ptr,
                                                  float* __restrict__ dinv,
                                                  float* __restrict__ xs1,
                                                  int* __restrict__ col, int E) {
    __shared__ int cntL[512];
    __shared__ int rsL[512];
    __shared__ int fillL[512];
    __shared__ int boffL[SCAN_BLKS];
    int t = threadIdx.x, b = blockIdx.x;
    int lo = b << BSHIFT;
    int nloc = min(512, N_NODES - lo);
    cntL[t] = 0;
    fillL[t] = 0;
    if (t < 64) {
        int orig = (t < SCAN_BLKS) ? bsum[t] : 0;
        int v = orig;
        for (int off = 1; off < 64; off <<= 1) {
            int up = __shfl_up(v, off);
            if (t >= off) v += up;
        }
        if (t < SCAN_BLKS) boffL[t] = v - orig;   // exclusive
    }
    __syncthreads();
    int i0 = b * NBLK;
    int start = hist[i0] + boffL[i0 >> 10];
    int end;
    if (b == NB_BUCKETS - 1) end = E;
    else {
        int i1 = (b + 1) * NBLK;
        end = hist[i1] + boffL[i1 >> 10];
    }
    for (int e = start + t; e < end; e += 512)
        atomicAdd(&cntL[packed[e] >> 17], 1);
    __syncthreads();
    int v = cntL[t];
    __syncthreads();
    for (int off = 1; off < 512; off <<= 1) {     // inclusive scan (Hillis-Steele)
        int add = (t >= off) ? cntL[t - off] : 0;
        __syncthreads();
        cntL[t] += add;
        __syncthreads();
    }
    int rowstart = start + cntL[t] - v;           // exclusive + bucket base
    rsL[t] = rowstart;
    if (t < nloc) {
        int node = lo + t;
        row_ptr[node] = rowstart;
        float d = rsqrtf((float)(v + 1));
        dinv[node] = d;
        const float4* xv = reinterpret_cast<const float4*>(x) + node * 2;
        float4 xa = xv[0], xb = xv[1];
        xa.x *= d; xa.y *= d; xa.z *= d; xa.w *= d;
        xb.x *= d; xb.y *= d; xb.z *= d; xb.w *= d;
        float4* xo = reinterpret_cast<float4*>(xs1) + node * 2;
        xo[0] = xa; xo[1] = xb;
    }
    if (b == NB_BUCKETS - 1 && t == 0) row_ptr[N_NODES] = E;
    __syncthreads();
    for (int e = start + t; e < end; e += 512) {
        int p = packed[e];
        int dl = p >> 17;
        int pos = rsL[dl] + atomicAdd(&fillL[dl], 1);
        col[pos] = p & 0x1FFFF;
    }
}

// Layer-1 aggregation FUSED with gemm1 (proven R13 form).
__global__ __launch_bounds__(256) void agg8g1_kernel(
        const float* __restrict__ xs, const int* __restrict__ row_ptr,
        const int* __restrict__ col, const float* __restrict__ dinv,
        const float* __restrict__ W1, const float* __restrict__ b1,
        float* __restrict__ xs2, int n) {
    int wave = threadIdx.x >> 6;            // 4 waves/block = 4 nodes/block
    int node = blockIdx.x * 4 + wave;
    if (node >= n) return;
    int lane = threadIdx.x & 63;
    int j = lane >> 1, l = lane & 1;
    int e0 = row_ptr[node], e1 = row_ptr[node + 1];
    float4 acc0 = {0.f, 0.f, 0.f, 0.f}, acc1 = acc0;
    if (j == 0) {   // self-loop term, counted once (2 lanes, one per half)
        const float4 sv = *reinterpret_cast<const float4*>(&xs[node * 8 + 4 * l]);
        acc0.x += sv.x; acc0.y += sv.y; acc0.z += sv.z; acc0.w += sv.w;
    }
    int base = e0;
    for (; base + 64 <= e1; base += 64) {   // 64 edges per iteration
        int s0 = __builtin_nontemporal_load(&col[base + j]);
        int s1 = __builtin_nontemporal_load(&col[base + 32 + j]);
        const float4 v0 = *reinterpret_cast<const float4*>(&xs[s0 * 8 + 4 * l]);
        const float4 v1 = *reinterpret_cast<const float4*>(&xs[s1 * 8 + 4 * l]);
        acc0.x += v0.x; acc0.y += v0.y; acc0.z += v0.z; acc0.w += v0.w;
        acc1.x += v1.x; acc1.y += v1.y; acc1.z += v1.z; acc1.w += v1.w;
    }
    if (base < e1) {                        // single masked pass (<=63 edges)
        int ee0 = base + j;
        int ee1 = base + 32 + j;
        int s0 = __builtin_nontemporal_load(&col[min(ee0, e1 - 1)]);
        int s1 = __builtin_nontemporal_load(&col[min(ee1, e1 - 1)]);
        float m0 = (ee0 < e1) ? 1.0f : 0.0f;
        float m1 = (ee1 < e1) ? 1.0f : 0.0f;
        const float4 v0 = *reinterpret_cast<const float4*>(&xs[s0 * 8 + 4 * l]);
        const float4 v1 = *reinterpret_cast<const float4*>(&xs[s1 * 8 + 4 * l]);
        acc0.x += m0 * v0.x; acc0.y += m0 * v0.y; acc0.z += m0 * v0.z; acc0.w += m0 * v0.w;
        acc1.x += m1 * v1.x; acc1.y += m1 * v1.y; acc1.z += m1 * v1.z; acc1.w += m1 * v1.w;
    }
    float4 r;
    r.x = acc0.x + acc1.x; r.y = acc0.y + acc1.y;
    r.z = acc0.z + acc1.z; r.w = acc0.w + acc1.w;
    r.x += __shfl_xor(r.x, 2);  r.y += __shfl_xor(r.y, 2);
    r.z += __shfl_xor(r.z, 2);  r.w += __shfl_xor(r.w, 2);
    r.x += __shfl_xor(r.x, 4);  r.y += __shfl_xor(r.y, 4);
    r.z += __shfl_xor(r.z, 4);  r.w += __shfl_xor(r.w, 4);
    r.x += __shfl_xor(r.x, 8);  r.y += __shfl_xor(r.y, 8);
    r.z += __shfl_xor(r.z, 8);  r.w += __shfl_xor(r.w, 8);
    r.x += __shfl_xor(r.x, 16); r.y += __shfl_xor(r.y, 16);
    r.z += __shfl_xor(r.z, 16); r.w += __shfl_xor(r.w, 16);
    r.x += __shfl_xor(r.x, 32); r.y += __shfl_xor(r.y, 32);
    r.z += __shfl_xor(r.z, 32); r.w += __shfl_xor(r.w, 32);
    float d = dinv[node];
    r.x *= d; r.y *= d; r.z *= d; r.w *= d;
    float z10 = __shfl(r.x, 0), z11 = __shfl(r.y, 0);
    float z12 = __shfl(r.z, 0), z13 = __shfl(r.w, 0);
    float z14 = __shfl(r.x, 1), z15 = __shfl(r.y, 1);
    float z16 = __shfl(r.z, 1), z17 = __shfl(r.w, 1);
    float a = b1[lane];
    a += z10 * W1[0 * 64 + lane];
    a += z11 * W1[1 * 64 + lane];
    a += z12 * W1[2 * 64 + lane];
    a += z13 * W1[3 * 64 + lane];
    a += z14 * W1[4 * 64 + lane];
    a += z15 * W1[5 * 64 + lane];
    a += z16 * W1[6 * 64 + lane];
    a += z17 * W1[7 * 64 + lane];
    xs2[node * 64 + lane] = d * fmaxf(a, 0.0f);
}

// D=64 aggregation, float4-per-lane gather, batched masked remainder.
// node0: SPLIT into two half-dispatches (visibility: drops the rocprof
// top-5 cutoff to ~52 us so the hidden mid-tier kernels surface).
__global__ __launch_bounds__(256) void agg64_kernel(
        const float* __restrict__ xs, const int* __restrict__ row_ptr,
        const int* __restrict__ col, const float* __restrict__ dinv,
        float* __restrict__ z, int node0, int nend) {
    int wave = threadIdx.x >> 6;            // 4 waves/block = 4 nodes/block
    int node = node0 + blockIdx.x * 4 + wave;
    if (node >= nend) return;
    int lane = threadIdx.x & 63;
    int j = lane >> 4, l = lane & 15;
    int e0 = row_ptr[node], e1 = row_ptr[node + 1];
    float4 acc0 = {0.f, 0.f, 0.f, 0.f}, acc1 = acc0, acc2 = acc0, acc3 = acc0;
    if (j == 0) {   // self-loop term, counted once
        const float4 sv = *reinterpret_cast<const float4*>(&xs[node * 64 + 4 * l]);
        acc0.x += sv.x; acc0.y += sv.y; acc0.z += sv.z; acc0.w += sv.w;
    }
    int base = e0;
    for (; base + 32 <= e1; base += 32) {   // 32 edges per iteration
        int s0 = __builtin_nontemporal_load(&col[base + j]);
        int s1 = __builtin_nontemporal_load(&col[base + 4 + j]);
        int s2 = __builtin_nontemporal_load(&col[base + 8 + j]);
        int s3 = __builtin_nontemporal_load(&col[base + 12 + j]);
        int s4 = __builtin_nontemporal_load(&col[base + 16 + j]);
        int s5 = __builtin_nontemporal_load(&col[base + 20 + j]);
        int s6 = __builtin_nontemporal_load(&col[base + 24 + j]);
        int s7 = __builtin_nontemporal_load(&col[base + 28 + j]);
        const float4 v0 = *reinterpret_cast<const float4*>(&xs[s0 * 64 + 4 * l]);
        const float4 v1 = *reinterpret_cast<const float4*>(&xs[s1 * 64 + 4 * l]);
        const float4 v2 = *reinterpret_cast<const float4*>(&xs[s2 * 64 + 4 * l]);
        const float4 v3 = *reinterpret_cast<const float4*>(&xs[s3 * 64 + 4 * l]);
        const float4 v4 = *reinterpret_cast<const float4*>(&xs[s4 * 64 + 4 * l]);
        const float4 v5 = *reinterpret_cast<const float4*>(&xs[s5 * 64 + 4 * l]);
        const float4 v6 = *reinterpret_cast<const float4*>(&xs[s6 * 64 + 4 * l]);
        const float4 v7 = *reinterpret_cast<const float4*>(&xs[s7 * 64 + 4 * l]);
        acc0.x += v0.x; acc0.y += v0.y; acc0.z += v0.z; acc0.w += v0.w;
        acc1.x += v1.x; acc1.y += v1.y; acc1.z += v1.z; acc1.w += v1.w;
        acc2.x += v2.x; acc2.y += v2.y; acc2.z += v2.z; acc2.w += v2.w;
        acc3.x += v3.x; acc3.y += v3.y; acc3.z += v3.z; acc3.w += v3.w;
        acc0.x += v4.x; acc0.y += v4.y; acc0.z += v4.z; acc0.w += v4.w;
        acc1.x += v5.x; acc1.y += v5.y; acc1.z += v5.z; acc1.w += v5.w;
        acc2.x += v6.x; acc2.y += v6.y; acc2.z += v6.z; acc2.w += v6.w;
        acc3.x += v7.x; acc3.y += v7.y; acc3.z += v7.z; acc3.w += v7.w;
    }
    if (base < e1) {   // single masked pass for <=31 remaining edges
        int ee0 = base + j,      ee1 = base + 4 + j;
        int ee2 = base + 8 + j,  ee3 = base + 12 + j;
        int ee4 = base + 16 + j, ee5 = base + 20 + j;
        int ee6 = base + 24 + j, ee7 = base + 28 + j;
        int s0 = __builtin_nontemporal_load(&col[min(ee0, e1 - 1)]);
        int s1 = __builtin_nontemporal_load(&col[min(ee1, e1 - 1)]);
        int s2 = __builtin_nontemporal_load(&col[min(ee2, e1 - 1)]);
        int s3 = __builtin_nontemporal_load(&col[min(ee3, e1 - 1)]);
        int s4 = __builtin_nontemporal_load(&col[min(ee4, e1 - 1)]);
        int s5 = __builtin_nontemporal_load(&col[min(ee5, e1 - 1)]);
        int s6 = __builtin_nontemporal_load(&col[min(ee6, e1 - 1)]);
        int s7 = __builtin_nontemporal_load(&col[min(ee7, e1 - 1)]);
        float m0 = (ee0 < e1) ? 1.f : 0.f, m1 = (ee1 < e1) ? 1.f : 0.f;
        float m2 = (ee2 < e1) ? 1.f : 0.f, m3 = (ee3 < e1) ? 1.f : 0.f;
        float m4 = (ee4 < e1) ? 1.f : 0.f, m5 = (ee5 < e1) ? 1.f : 0.f;
        float m6 = (ee6 < e1) ? 1.f : 0.f, m7 = (ee7 < e1) ? 1.f : 0.f;
        const float4 v0 = *reinterpret_cast<const float4*>(&xs[s0 * 64 + 4 * l]);
        const float4 v1 = *reinterpret_cast<const float4*>(&xs[s1 * 64 + 4 * l]);
        const float4 v2 = *reinterpret_cast<const float4*>(&xs[s2 * 64 + 4 * l]);
        const float4 v3 = *reinterpret_cast<const float4*>(&xs[s3 * 64 + 4 * l]);
        const float4 v4 = *reinterpret_cast<const float4*>(&xs[s4 * 64 + 4 * l]);
        const float4 v5 = *reinterpret_cast<const float4*>(&xs[s5 * 64 + 4 * l]);
        const float4 v6 = *reinterpret_cast<const float4*>(&xs[s6 * 64 + 4 * l]);
        const float4 v7 = *reinterpret_cast<const float4*>(&xs[s7 * 64 + 4 * l]);
        acc0.x += m0 * v0.x; acc0.y += m0 * v0.y; acc0.z += m0 * v0.z; acc0.w += m0 * v0.w;
        acc1.x += m1 * v1.x; acc1.y += m1 * v1.y; acc1.z += m1 * v1.z; acc1.w += m1 * v1.w;
        acc2.x += m2 * v2.x; acc2.y += m2 * v2.y; acc2.z += m2 * v2.z; acc2.w += m2 * v2.w;
        acc3.x += m3 * v3.x; acc3.y += m3 * v3.y; acc3.z += m3 * v3.z; acc3.w += m3 * v3.w;
        acc0.x += m4 * v4.x; acc0.y += m4 * v4.y; acc0.z += m4 * v4.z; acc0.w += m4 * v4.w;
        acc1.x += m5 * v5.x; acc1.y += m5 * v5.y; acc1.z += m5 * v5.z; acc1.w += m5 * v5.w;
        acc2.x += m6 * v6.x; acc2.y += m6 * v6.y; acc2.z += m6 * v6.z; acc2.w += m6 * v6.w;
        acc3.x += m7 * v7.x; acc3.y += m7 * v7.y; acc3.z += m7 * v7.z; acc3.w += m7 * v7.w;
    }
    float4 r;
    r.x = (acc0.x + acc1.x) + (acc2.x + acc3.x);
    r.y = (acc0.y + acc1.y) + (acc2.y + acc3.y);
    r.z = (acc0.z + acc1.z) + (acc2.z + acc3.z);
    r.w = (acc0.w + acc1.w) + (acc2.w + acc3.w);
    r.x += __shfl_xor(r.x, 16); r.y += __shfl_xor(r.y, 16);
    r.z += __shfl_xor(r.z, 16); r.w += __shfl_xor(r.w, 16);
    r.x += __shfl_xor(r.x, 32); r.y += __shfl_xor(r.y, 32);
    r.z += __shfl_xor(r.z, 32); r.w += __shfl_xor(r.w, 32);
    if (j == 0) {
        float d = dinv[node];
        r.x *= d; r.y *= d; r.z *= d; r.w *= d;
        *reinterpret_cast<float4*>(&z[node * 64 + 4 * l]) = r;
    }
}

// Y[row, :] = opt_scale(dinv[row]) * opt_relu( X[row,:] @ W + opt_bias )
// Register-blocked 4x4, bounded unroll (R16 proven form).
template <int K, int M, bool BIAS, bool RELU, bool SCALE>
__global__ __launch_bounds__(256) void gemm_kernel(
        const float* __restrict__ X, const float* __restrict__ W,
        const float* __restrict__ b, const float* __restrict__ dinv,
        float* __restrict__ Y, int nrows) {
    constexpr int CG = M / 4;          // col-groups (gemm2: 32, gemm3: 16)
    constexpr int RG = 256 / CG;       // row-groups  (gemm2: 8,  gemm3: 16)
    constexpr int ROWS = RG * 4;       // rows/tile   (gemm2: 32, gemm3: 64)
    constexpr int XSTR = K + 4;        // padded X stride (bank decorrelation)
    __shared__ float Wl[K * M];        // 32 KB
    __shared__ float Xl[ROWS * XSTR];
    __shared__ float Bl[M];
    int tid = threadIdx.x;
    {   // float4 weight staging
        const float4* Wv = reinterpret_cast<const float4*>(W);
        float4* Wlv = reinterpret_cast<float4*>(Wl);
        for (int i = tid; i < K * M / 4; i += 256) Wlv[i] = Wv[i];
    }
    if (tid < M) Bl[tid] = BIAS ? b[tid] : 0.0f;
    int cg = tid % CG;
    int rg = tid / CG;
    int ntiles = (nrows + ROWS - 1) / ROWS;
    for (int tile = blockIdx.x; tile < ntiles; tile += gridDim.x) {
        int row0 = tile * ROWS;
        __syncthreads();
        {   // stage X tile (float4, padded rows, zero-fill tail)
            int base4 = row0 * (K / 4);
            int tot4 = nrows * (K / 4);
            for (int i = tid; i < ROWS * K / 4; i += 256) {
                float4 v = {0.f, 0.f, 0.f, 0.f};
                if (base4 + i < tot4) v = reinterpret_cast<const float4*>(X)[base4 + i];
                int rr = i / (K / 4), kk = i % (K / 4);
                *reinterpret_cast<float4*>(&Xl[rr * XSTR + kk * 4]) = v;
            }
        }
        __syncthreads();
        float4 acc[4];
#pragma unroll
        for (int rr = 0; rr < 4; ++rr)
            acc[rr] = *reinterpret_cast<const float4*>(&Bl[cg * 4]);
#pragma unroll 1
        for (int k = 0; k < K; k += 4) {
            const float4 w0 = *reinterpret_cast<const float4*>(&Wl[(k + 0) * M + cg * 4]);
            const float4 w1 = *reinterpret_cast<const float4*>(&Wl[(k + 1) * M + cg * 4]);
            const float4 w2 = *reinterpret_cast<const float4*>(&Wl[(k + 2) * M + cg * 4]);
            const float4 w3 = *reinterpret_cast<const float4*>(&Wl[(k + 3) * M + cg * 4]);
#pragma unroll
            for (int rr = 0; rr < 4; ++rr) {
                const float4 xv = *reinterpret_cast<const float4*>(
                    &Xl[(rg * 4 + rr) * XSTR + k]);
                acc[rr].x += xv.x * w0.x + xv.y * w1.x + xv.z * w2.x + xv.w * w3.x;
                acc[rr].y += xv.x * w0.y + xv.y * w1.y + xv.z * w2.y + xv.w * w3.y;
                acc[rr].z += xv.x * w0.z + xv.y * w1.z + xv.z * w2.z + xv.w * w3.z;
                acc[rr].w += xv.x * w0.w + xv.y * w1.w + xv.z * w2.w + xv.w * w3.w;
            }
        }
#pragma unroll
        for (int rr = 0; rr < 4; ++rr) {
            int row = row0 + rg * 4 + rr;
            if (row < nrows) {
                float4 a = acc[rr];
                if constexpr (RELU) {
                    a.x = fmaxf(a.x, 0.f); a.y = fmaxf(a.y, 0.f);
                    a.z = fmaxf(a.z, 0.f); a.w = fmaxf(a.w, 0.f);
                }
                if constexpr (SCALE) {
                    float d = dinv[row];
                    a.x *= d; a.y *= d; a.z *= d; a.w *= d;
                }
                *reinterpret_cast<float4*>(&Y[row * M + cg * 4]) = a;
            }
        }
    }
}

// h3 = relu(z3 + b3); pool sums/counts per graph.
#define POOL_NPB 1024   // nodes per block
__global__ __launch_bounds__(256) void pool_kernel(
        const float* __restrict__ z3, const float* __restrict__ b3,
        const int* __restrict__ batch, float* __restrict__ sums,
        float* __restrict__ cntf, int n) {
    int wave = threadIdx.x >> 6;
    int lane = threadIdx.x & 63;   // feature index
    int node0 = blockIdx.x * POOL_NPB;
    int nodeEnd = node0 + POOL_NPB;
    if (nodeEnd > n) nodeEnd = n;
    float bias = b3[lane];
    float acc = 0.0f, cnt = 0.0f;
    int curg = -1;
    for (int node = node0 + wave; node < nodeEnd; node += 4) {
        int g = batch[node];               // wave-uniform (lane = feature)
        if (g != curg) {                   // wave-uniform branch
            if (curg >= 0) {
                atomicAdd(&sums[curg * 64 + lane], acc);
                if (lane == 0) atomicAdd(&cntf[curg], cnt);
            }
            curg = g; acc = 0.0f; cnt = 0.0f;
        }
        acc += fmaxf(__builtin_nontemporal_load(&z3[node * 64 + lane]) + bias, 0.0f);
        cnt += 1.0f;
    }
    if (curg >= 0) {
        atomicAdd(&sums[curg * 64 + lane], acc);
        if (lane == 0) atomicAdd(&cntf[curg], cnt);
    }
}

// per-graph: g = sums/max(cnt,1); hid = relu(g@Wl1+bl1); out = hid@Wl2+bl2
__global__ void mlp_kernel(const float* __restrict__ sums, const float* __restrict__ cntf,
                           const float* __restrict__ Wl1, const float* __restrict__ bl1,
                           const float* __restrict__ Wl2, const float* __restrict__ bl2,
                           float* __restrict__ out) {
    __shared__ float gv[64];
    __shared__ float hid[32];
    int g = blockIdx.x, t = threadIdx.x;
    float denom = fmaxf(cntf[g], 1.0f);
    gv[t] = sums[g * 64 + t] / denom;
    __syncthreads();
    if (t < 32) {
        float a = bl1[t];
#pragma unroll
        for (int k = 0; k < 64; ++k) a += gv[k] * Wl1[k * 32 + t];
        hid[t] = fmaxf(a, 0.0f);
    }
    __syncthreads();
    if (t == 0) {
        float o = bl2[0];
#pragma unroll
        for (int k = 0; k < 32; ++k) o += hid[k] * Wl2[k];
        out[g] = o;
    }
}

extern "C" void kernel_launch(void* const* d_in, const int* in_sizes, int n_in,
                              void* d_out, int out_size, void* d_ws, size_t ws_size,
                              hipStream_t stream) {
    const float* x   = (const float*)d_in[0];
    const int* ei    = (const int*)d_in[1];
    const int* batch = (const int*)d_in[2];
    const float* W1  = (const float*)d_in[3];
    const float* b1  = (const float*)d_in[4];
    const float* W2  = (const float*)d_in[5];
    const float* b2  = (const float*)d_in[6];
    const float* W3  = (const float*)d_in[7];
    const float* b3  = (const float*)d_in[8];
    const float* Wl1 = (const float*)d_in[9];
    const float* bl1 = (const float*)d_in[10];
    const float* Wl2 = (const float*)d_in[11];
    const float* bl2 = (const float*)d_in[12];
    float* out = (float*)d_out;

    const int N = N_NODES;
    const int E = in_sizes[1] / 2;   // 3.2M
    const int* src = ei;
    const int* dst = ei + E;

    char* ws = (char*)d_ws;
    float* sums    = (float*)(ws + OFF_SUMS);
    float* cntf    = (float*)(ws + OFF_CNTF);
    int*   hist    = (int*)(ws + OFF_HIST);
    int*   bsum    = (int*)(ws + OFF_BSUM);
    int*   row_ptr = (int*)(ws + OFF_ROWPTR);
    float* dinv    = (float*)(ws + OFF_DINV);
    int*   col     = (int*)(ws + OFF_COL);
    float* xs1     = (float*)(ws + OFF_XS1);
    float* bufQ    = (float*)(ws + OFF_BUFQ);   // xs2, later z3
    float* bufR    = (float*)(ws + OFF_BUFR);   // z2, later ys
    float* bufP    = (float*)(ws + OFF_BUFP);   // h2
    int*   packed  = (int*)(ws + OFF_PAIRS);    // aliases bufP (dead before h2)

    // CSR build: hist(+zero) -> scanA -> bin -> csr(+xs1 scale)
    int epb = (E + NBLK - 1) / NBLK;   // 12500
    hist_kernel<<<NBLK, 256, 0, stream>>>(dst, hist, (int*)ws, E, epb);
    scanhA_kernel<<<SCAN_BLKS, 1024, 0, stream>>>(hist, bsum);
    bin_kernel<<<NBLK, 256, 0, stream>>>(src, dst, hist, bsum, packed, E, epb);
    csr_kernel<<<NB_BUCKETS, 512, 0, stream>>>(packed, hist, bsum, x,
                                               row_ptr, dinv, xs1, col, E);

    // Layer 1 (agg + gemm1 fused): xs2 = dinv*relu((agg xs1)@W1+b1)
    agg8g1_kernel<<<(N + 3) / 4, 256, 0, stream>>>(xs1, row_ptr, col, dinv, W1, b1, bufQ, N);

    // Layer 2: z2 = agg(xs2) [split halves] ; h2 = relu(z2@W2+b2)
    const int HALF = N / 2;   // 50000
    agg64_kernel<<<(HALF + 3) / 4, 256, 0, stream>>>(bufQ, row_ptr, col, dinv, bufR, 0, HALF);
    agg64_kernel<<<(N - HALF + 3) / 4, 256, 0, stream>>>(bufQ, row_ptr, col, dinv, bufR, HALF, N);
    gemm_kernel<64, 128, true, true, false><<<3125, 256, 0, stream>>>(bufR, W2, b2, nullptr, bufP, N);

    // Layer 3: ys = dinv*(h2@W3) ; z3 = agg(ys) [split halves]
    gemm_kernel<128, 64, false, false, true><<<1563, 256, 0, stream>>>(bufP, W3, nullptr, dinv, bufR, N);
    agg64_kernel<<<(HALF + 3) / 4, 256, 0, stream>>>(bufR, row_ptr, col, dinv, bufQ, 0, HALF);
    agg64_kernel<<<(N - HALF + 3) / 4, 256, 0, stream>>>(bufR, row_ptr, col, dinv, bufQ, HALF, N);

    // Pool + MLP head
    pool_kernel<<<(N + POOL_NPB - 1) / POOL_NPB, 256, 0, stream>>>(bufQ, b3, batch, sums, cntf, N);
    mlp_kernel<<<N_GRAPHS, 64, 0, stream>>>(sums, cntf, Wl1, bl1, Wl2, bl2, out);
}

// Round 18
// 519.668 us; speedup vs baseline: 1.1342x; 1.1342x over previous
//
#include <hip/hip_runtime.h>
#include <hip/hip_bf16.h>

#define N_NODES 100000
#define N_EDGES 3200000
#define N_GRAPHS 256
#define NB_BUCKETS 196      // ceil(100000 / 512)
#define BSHIFT 9            // 512 nodes per bucket
#define NBLK 256            // blocks for hist/bin passes
#define SCAN_BLKS 49        // 50176 / 1024

// ---------------- workspace layout (bytes) ----------------
#define OFF_SUMS      0u            // float[256*64] pool sums (zeroed in hist)
#define OFF_CNTF      65536u        // float[256] pool counts (zeroed in hist)
#define ZERO_BYTES    66560u
#define OFF_HIST      66560u        // int[196*256] (bucket-major) per-(bucket,block) counts
#define OFF_BSUM      267264u       // int[64] scan block sums
#define OFF_ROWPTR    267776u       // int[N+1]
#define OFF_DINV      668160u       // float[N]
#define OFF_COL       1068544u      // int[E]
#define OFF_XS1       13868544u     // float[N*8]
#define OFF_BUFQ      20268544u     // float[N*64]  xs2, later z3
#define OFF_BUFR      45868544u     // float[N*64]  z2, later ys
#define OFF_BUFP      71468544u     // float[N*128] h2; ALIASED: packed[E] (dead before h2)
#define OFF_PAIRS     OFF_BUFP
// total ~122.7 MB (proven through R17)

// ---- P1: per-(bucket,block) histogram of dst. Also zeroes the pool
// accumulators (was a separate zero_kernel dispatch).
__global__ __launch_bounds__(256) void hist_kernel(const int* __restrict__ dst,
                                                   int* __restrict__ hist,
                                                   int* __restrict__ zbase,
                                                   int E, int epb) {
    __shared__ int h[NB_BUCKETS];
    int t = threadIdx.x, blk = blockIdx.x;
    int gid = blk * 256 + t;
    if (gid < (int)(ZERO_BYTES / 4)) zbase[gid] = 0;
    if (t < NB_BUCKETS) h[t] = 0;
    __syncthreads();
    int e0 = blk * epb, e1 = min(e0 + epb, E);
    for (int e = e0 + t; e < e1; e += 256)
        atomicAdd(&h[__builtin_nontemporal_load(&dst[e]) >> BSHIFT], 1);
    __syncthreads();
    if (t < NB_BUCKETS) hist[t * NBLK + blk] = h[t];
}

// ---- P2: block-local exclusive scan of hist[50176] + per-block sums.
__global__ __launch_bounds__(1024) void scanhA_kernel(int* __restrict__ hist,
                                                      int* __restrict__ bsum) {
    __shared__ int s[1024];
    int t = threadIdx.x;
    int i = blockIdx.x * 1024 + t;     // 49*1024 == 50176 exactly
    int v = hist[i];
    s[t] = v;
    __syncthreads();
    for (int off = 1; off < 1024; off <<= 1) {
        int add = (t >= off) ? s[t - off] : 0;
        __syncthreads();
        s[t] += add;
        __syncthreads();
    }
    hist[i] = s[t] - v;                // block-local exclusive
    if (t == 1023) bsum[blockIdx.x] = s[t];
}

// ---- P3: bin edges, PACKED (dl<<17 | src), local offset scan.
__global__ __launch_bounds__(256) void bin_kernel(const int* __restrict__ src,
                                                  const int* __restrict__ dst,
                                                  const int* __restrict__ hist,
                                                  const int* __restrict__ bsum,
                                                  int* __restrict__ packed, int E, int epb) {
    __shared__ int cur[NB_BUCKETS];
    __shared__ int boffL[SCAN_BLKS];
    int t = threadIdx.x, blk = blockIdx.x;
    if (t < 64) {
        int orig = (t < SCAN_BLKS) ? bsum[t] : 0;
        int v = orig;
        for (int off = 1; off < 64; off <<= 1) {
            int up = __shfl_up(v, off);
            if (t >= off) v += up;
        }
        if (t < SCAN_BLKS) boffL[t] = v - orig;   // exclusive
    }
    __syncthreads();
    if (t < NB_BUCKETS) {
        int i = t * NBLK + blk;
        cur[t] = hist[i] + boffL[i >> 10];
    }
    __syncthreads();
    int e0 = blk * epb, e1 = min(e0 + epb, E);
    for (int e = e0 + t; e < e1; e += 256) {
        int d = __builtin_nontemporal_load(&dst[e]);
        int sv = __builtin_nontemporal_load(&src[e]);
        int pos = atomicAdd(&cur[d >> BSHIFT], 1);
        packed[pos] = ((d & 511) << 17) | sv;
    }
}

// ---- P4: per-bucket CSR finalize (row_ptr, dinv, col) + xs1 = dinv*x.
__global__ __launch_bounds__(512) void csr_kernel(const int* __restrict__ packed,
                                                  const int* __restrict__ hist,
                                                  const int* __restrict__ bsum,
                                                  const float* __restrict__ x,
                                                  int* __restrict__ row_ptr,
                                                  float* __restrict__ dinv,
                                                  float* __restrict__ xs1,
                                                  int* __restrict__ col, int E) {
    __shared__ int cntL[512];
    __shared__ int rsL[512];
    __shared__ int fillL[512];
    __shared__ int boffL[SCAN_BLKS];
    int t = threadIdx.x, b = blockIdx.x;
    int lo = b << BSHIFT;
    int nloc = min(512, N_NODES - lo);
    cntL[t] = 0;
    fillL[t] = 0;
    if (t < 64) {
        int orig = (t < SCAN_BLKS) ? bsum[t] : 0;
        int v = orig;
        for (int off = 1; off < 64; off <<= 1) {
            int up = __shfl_up(v, off);
            if (t >= off) v += up;
        }
        if (t < SCAN_BLKS) boffL[t] = v - orig;   // exclusive
    }
    __syncthreads();
    int i0 = b * NBLK;
    int start = hist[i0] + boffL[i0 >> 10];
    int end;
    if (b == NB_BUCKETS - 1) end = E;
    else {
        int i1 = (b + 1) * NBLK;
        end = hist[i1] + boffL[i1 >> 10];
    }
    for (int e = start + t; e < end; e += 512)
        atomicAdd(&cntL[packed[e] >> 17], 1);
    __syncthreads();
    int v = cntL[t];
    __syncthreads();
    for (int off = 1; off < 512; off <<= 1) {     // inclusive scan (Hillis-Steele)
        int add = (t >= off) ? cntL[t - off] : 0;
        __syncthreads();
        cntL[t] += add;
        __syncthreads();
    }
    int rowstart = start + cntL[t] - v;           // exclusive + bucket base
    rsL[t] = rowstart;
    if (t < nloc) {
        int node = lo + t;
        row_ptr[node] = rowstart;
        float d = rsqrtf((float)(v + 1));
        dinv[node] = d;
        const float4* xv = reinterpret_cast<const float4*>(x) + node * 2;
        float4 xa = xv[0], xb = xv[1];
        xa.x *= d; xa.y *= d; xa.z *= d; xa.w *= d;
        xb.x *= d; xb.y *= d; xb.z *= d; xb.w *= d;
        float4* xo = reinterpret_cast<float4*>(xs1) + node * 2;
        xo[0] = xa; xo[1] = xb;
    }
    if (b == NB_BUCKETS - 1 && t == 0) row_ptr[N_NODES] = E;
    __syncthreads();
    for (int e = start + t; e < end; e += 512) {
        int p = packed[e];
        int dl = p >> 17;
        int pos = rsL[dl] + atomicAdd(&fillL[dl], 1);
        col[pos] = p & 0x1FFFF;
    }
}

// Layer-1 aggregation FUSED with gemm1 (proven R13 form).
__global__ __launch_bounds__(256) void agg8g1_kernel(
        const float* __restrict__ xs, const int* __restrict__ row_ptr,
        const int* __restrict__ col, const float* __restrict__ dinv,
        const float* __restrict__ W1, const float* __restrict__ b1,
        float* __restrict__ xs2, int n) {
    int wave = threadIdx.x >> 6;            // 4 waves/block = 4 nodes/block
    int node = blockIdx.x * 4 + wave;
    if (node >= n) return;
    int lane = threadIdx.x & 63;
    int j = lane >> 1, l = lane & 1;
    int e0 = row_ptr[node], e1 = row_ptr[node + 1];
    float4 acc0 = {0.f, 0.f, 0.f, 0.f}, acc1 = acc0;
    if (j == 0) {   // self-loop term, counted once (2 lanes, one per half)
        const float4 sv = *reinterpret_cast<const float4*>(&xs[node * 8 + 4 * l]);
        acc0.x += sv.x; acc0.y += sv.y; acc0.z += sv.z; acc0.w += sv.w;
    }
    int base = e0;
    for (; base + 64 <= e1; base += 64) {   // 64 edges per iteration
        int s0 = __builtin_nontemporal_load(&col[base + j]);
        int s1 = __builtin_nontemporal_load(&col[base + 32 + j]);
        const float4 v0 = *reinterpret_cast<const float4*>(&xs[s0 * 8 + 4 * l]);
        const float4 v1 = *reinterpret_cast<const float4*>(&xs[s1 * 8 + 4 * l]);
        acc0.x += v0.x; acc0.y += v0.y; acc0.z += v0.z; acc0.w += v0.w;
        acc1.x += v1.x; acc1.y += v1.y; acc1.z += v1.z; acc1.w += v1.w;
    }
    if (base < e1) {                        // single masked pass (<=63 edges)
        int ee0 = base + j;
        int ee1 = base + 32 + j;
        int s0 = __builtin_nontemporal_load(&col[min(ee0, e1 - 1)]);
        int s1 = __builtin_nontemporal_load(&col[min(ee1, e1 - 1)]);
        float m0 = (ee0 < e1) ? 1.0f : 0.0f;
        float m1 = (ee1 < e1) ? 1.0f : 0.0f;
        const float4 v0 = *reinterpret_cast<const float4*>(&xs[s0 * 8 + 4 * l]);
        const float4 v1 = *reinterpret_cast<const float4*>(&xs[s1 * 8 + 4 * l]);
        acc0.x += m0 * v0.x; acc0.y += m0 * v0.y; acc0.z += m0 * v0.z; acc0.w += m0 * v0.w;
        acc1.x += m1 * v1.x; acc1.y += m1 * v1.y; acc1.z += m1 * v1.z; acc1.w += m1 * v1.w;
    }
    float4 r;
    r.x = acc0.x + acc1.x; r.y = acc0.y + acc1.y;
    r.z = acc0.z + acc1.z; r.w = acc0.w + acc1.w;
    r.x += __shfl_xor(r.x, 2);  r.y += __shfl_xor(r.y, 2);
    r.z += __shfl_xor(r.z, 2);  r.w += __shfl_xor(r.w, 2);
    r.x += __shfl_xor(r.x, 4);  r.y += __shfl_xor(r.y, 4);
    r.z += __shfl_xor(r.z, 4);  r.w += __shfl_xor(r.w, 4);
    r.x += __shfl_xor(r.x, 8);  r.y += __shfl_xor(r.y, 8);
    r.z += __shfl_xor(r.z, 8);  r.w += __shfl_xor(r.w, 8);
    r.x += __shfl_xor(r.x, 16); r.y += __shfl_xor(r.y, 16);
    r.z += __shfl_xor(r.z, 16); r.w += __shfl_xor(r.w, 16);
    r.x += __shfl_xor(r.x, 32); r.y += __shfl_xor(r.y, 32);
    r.z += __shfl_xor(r.z, 32); r.w += __shfl_xor(r.w, 32);
    float d = dinv[node];
    r.x *= d; r.y *= d; r.z *= d; r.w *= d;
    float z10 = __shfl(r.x, 0), z11 = __shfl(r.y, 0);
    float z12 = __shfl(r.z, 0), z13 = __shfl(r.w, 0);
    float z14 = __shfl(r.x, 1), z15 = __shfl(r.y, 1);
    float z16 = __shfl(r.z, 1), z17 = __shfl(r.w, 1);
    float a = b1[lane];
    a += z10 * W1[0 * 64 + lane];
    a += z11 * W1[1 * 64 + lane];
    a += z12 * W1[2 * 64 + lane];
    a += z13 * W1[3 * 64 + lane];
    a += z14 * W1[4 * 64 + lane];
    a += z15 * W1[5 * 64 + lane];
    a += z16 * W1[6 * 64 + lane];
    a += z17 * W1[7 * 64 + lane];
    xs2[node * 64 + lane] = d * fmaxf(a, 0.0f);
}

// D=64 aggregation, float4-per-lane gather, batched masked remainder.
// Split into two half-dispatches (profiling visibility; ~neutral).
__global__ __launch_bounds__(256) void agg64_kernel(
        const float* __restrict__ xs, const int* __restrict__ row_ptr,
        const int* __restrict__ col, const float* __restrict__ dinv,
        float* __restrict__ z, int node0, int nend) {
    int wave = threadIdx.x >> 6;            // 4 waves/block = 4 nodes/block
    int node = node0 + blockIdx.x * 4 + wave;
    if (node >= nend) return;
    int lane = threadIdx.x & 63;
    int j = lane >> 4, l = lane & 15;
    int e0 = row_ptr[node], e1 = row_ptr[node + 1];
    float4 acc0 = {0.f, 0.f, 0.f, 0.f}, acc1 = acc0, acc2 = acc0, acc3 = acc0;
    if (j == 0) {   // self-loop term, counted once
        const float4 sv = *reinterpret_cast<const float4*>(&xs[node * 64 + 4 * l]);
        acc0.x += sv.x; acc0.y += sv.y; acc0.z += sv.z; acc0.w += sv.w;
    }
    int base = e0;
    for (; base + 32 <= e1; base += 32) {   // 32 edges per iteration
        int s0 = __builtin_nontemporal_load(&col[base + j]);
        int s1 = __builtin_nontemporal_load(&col[base + 4 + j]);
        int s2 = __builtin_nontemporal_load(&col[base + 8 + j]);
        int s3 = __builtin_nontemporal_load(&col[base + 12 + j]);
        int s4 = __builtin_nontemporal_load(&col[base + 16 + j]);
        int s5 = __builtin_nontemporal_load(&col[base + 20 + j]);
        int s6 = __builtin_nontemporal_load(&col[base + 24 + j]);
        int s7 = __builtin_nontemporal_load(&col[base + 28 + j]);
        const float4 v0 = *reinterpret_cast<const float4*>(&xs[s0 * 64 + 4 * l]);
        const float4 v1 = *reinterpret_cast<const float4*>(&xs[s1 * 64 + 4 * l]);
        const float4 v2 = *reinterpret_cast<const float4*>(&xs[s2 * 64 + 4 * l]);
        const float4 v3 = *reinterpret_cast<const float4*>(&xs[s3 * 64 + 4 * l]);
        const float4 v4 = *reinterpret_cast<const float4*>(&xs[s4 * 64 + 4 * l]);
        const float4 v5 = *reinterpret_cast<const float4*>(&xs[s5 * 64 + 4 * l]);
        const float4 v6 = *reinterpret_cast<const float4*>(&xs[s6 * 64 + 4 * l]);
        const float4 v7 = *reinterpret_cast<const float4*>(&xs[s7 * 64 + 4 * l]);
        acc0.x += v0.x; acc0.y += v0.y; acc0.z += v0.z; acc0.w += v0.w;
        acc1.x += v1.x; acc1.y += v1.y; acc1.z += v1.z; acc1.w += v1.w;
        acc2.x += v2.x; acc2.y += v2.y; acc2.z += v2.z; acc2.w += v2.w;
        acc3.x += v3.x; acc3.y += v3.y; acc3.z += v3.z; acc3.w += v3.w;
        acc0.x += v4.x; acc0.y += v4.y; acc0.z += v4.z; acc0.w += v4.w;
        acc1.x += v5.x; acc1.y += v5.y; acc1.z += v5.z; acc1.w += v5.w;
        acc2.x += v6.x; acc2.y += v6.y; acc2.z += v6.z; acc2.w += v6.w;
        acc3.x += v7.x; acc3.y += v7.y; acc3.z += v7.z; acc3.w += v7.w;
    }
    if (base < e1) {   // single masked pass for <=31 remaining edges
        int ee0 = base + j,      ee1 = base + 4 + j;
        int ee2 = base + 8 + j,  ee3 = base + 12 + j;
        int ee4 = base + 16 + j, ee5 = base + 20 + j;
        int ee6 = base + 24 + j, ee7 = base + 28 + j;
        int s0 = __builtin_nontemporal_load(&col[min(ee0, e1 - 1)]);
        int s1 = __builtin_nontemporal_load(&col[min(ee1, e1 - 1)]);
        int s2 = __builtin_nontemporal_load(&col[min(ee2, e1 - 1)]);
        int s3 = __builtin_nontemporal_load(&col[min(ee3, e1 - 1)]);
        int s4 = __builtin_nontemporal_load(&col[min(ee4, e1 - 1)]);
        int s5 = __builtin_nontemporal_load(&col[min(ee5, e1 - 1)]);
        int s6 = __builtin_nontemporal_load(&col[min(ee6, e1 - 1)]);
        int s7 = __builtin_nontemporal_load(&col[min(ee7, e1 - 1)]);
        float m0 = (ee0 < e1) ? 1.f : 0.f, m1 = (ee1 < e1) ? 1.f : 0.f;
        float m2 = (ee2 < e1) ? 1.f : 0.f, m3 = (ee3 < e1) ? 1.f : 0.f;
        float m4 = (ee4 < e1) ? 1.f : 0.f, m5 = (ee5 < e1) ? 1.f : 0.f;
        float m6 = (ee6 < e1) ? 1.f : 0.f, m7 = (ee7 < e1) ? 1.f : 0.f;
        const float4 v0 = *reinterpret_cast<const float4*>(&xs[s0 * 64 + 4 * l]);
        const float4 v1 = *reinterpret_cast<const float4*>(&xs[s1 * 64 + 4 * l]);
        const float4 v2 = *reinterpret_cast<const float4*>(&xs[s2 * 64 + 4 * l]);
        const float4 v3 = *reinterpret_cast<const float4*>(&xs[s3 * 64 + 4 * l]);
        const float4 v4 = *reinterpret_cast<const float4*>(&xs[s4 * 64 + 4 * l]);
        const float4 v5 = *reinterpret_cast<const float4*>(&xs[s5 * 64 + 4 * l]);
        const float4 v6 = *reinterpret_cast<const float4*>(&xs[s6 * 64 + 4 * l]);
        const float4 v7 = *reinterpret_cast<const float4*>(&xs[s7 * 64 + 4 * l]);
        acc0.x += m0 * v0.x; acc0.y += m0 * v0.y; acc0.z += m0 * v0.z; acc0.w += m0 * v0.w;
        acc1.x += m1 * v1.x; acc1.y += m1 * v1.y; acc1.z += m1 * v1.z; acc1.w += m1 * v1.w;
        acc2.x += m2 * v2.x; acc2.y += m2 * v2.y; acc2.z += m2 * v2.z; acc2.w += m2 * v2.w;
        acc3.x += m3 * v3.x; acc3.y += m3 * v3.y; acc3.z += m3 * v3.z; acc3.w += m3 * v3.w;
        acc0.x += m4 * v4.x; acc0.y += m4 * v4.y; acc0.z += m4 * v4.z; acc0.w += m4 * v4.w;
        acc1.x += m5 * v5.x; acc1.y += m5 * v5.y; acc1.z += m5 * v5.z; acc1.w += m5 * v5.w;
        acc2.x += m6 * v6.x; acc2.y += m6 * v6.y; acc2.z += m6 * v6.z; acc2.w += m6 * v6.w;
        acc3.x += m7 * v7.x; acc3.y += m7 * v7.y; acc3.z += m7 * v7.z; acc3.w += m7 * v7.w;
    }
    float4 r;
    r.x = (acc0.x + acc1.x) + (acc2.x + acc3.x);
    r.y = (acc0.y + acc1.y) + (acc2.y + acc3.y);
    r.z = (acc0.z + acc1.z) + (acc2.z + acc3.z);
    r.w = (acc0.w + acc1.w) + (acc2.w + acc3.w);
    r.x += __shfl_xor(r.x, 16); r.y += __shfl_xor(r.y, 16);
    r.z += __shfl_xor(r.z, 16); r.w += __shfl_xor(r.w, 16);
    r.x += __shfl_xor(r.x, 32); r.y += __shfl_xor(r.y, 32);
    r.z += __shfl_xor(r.z, 32); r.w += __shfl_xor(r.w, 32);
    if (j == 0) {
        float d = dinv[node];
        r.x *= d; r.y *= d; r.z *= d; r.w *= d;
        *reinterpret_cast<float4*>(&z[node * 64 + 4 * l]) = r;
    }
}

// Y[row, :] = opt_scale(dinv[row]) * opt_relu( X[row,:] @ W + opt_bias )
// Register-blocked 4x4, bounded unroll (R16 proven form).
template <int K, int M, bool BIAS, bool RELU, bool SCALE>
__global__ __launch_bounds__(256) void gemm_kernel(
        const float* __restrict__ X, const float* __restrict__ W,
        const float* __restrict__ b, const float* __restrict__ dinv,
        float* __restrict__ Y, int nrows) {
    constexpr int CG = M / 4;          // col-groups (gemm2: 32, gemm3: 16)
    constexpr int RG = 256 / CG;       // row-groups  (gemm2: 8,  gemm3: 16)
    constexpr int ROWS = RG * 4;       // rows/tile   (gemm2: 32, gemm3: 64)
    constexpr int XSTR = K + 4;        // padded X stride (bank decorrelation)
    __shared__ float Wl[K * M];        // 32 KB
    __shared__ float Xl[ROWS * XSTR];
    __shared__ float Bl[M];
    int tid = threadIdx.x;
    {   // float4 weight staging
        const float4* Wv = reinterpret_cast<const float4*>(W);
        float4* Wlv = reinterpret_cast<float4*>(Wl);
        for (int i = tid; i < K * M / 4; i += 256) Wlv[i] = Wv[i];
    }
    if (tid < M) Bl[tid] = BIAS ? b[tid] : 0.0f;
    int cg = tid % CG;
    int rg = tid / CG;
    int ntiles = (nrows + ROWS - 1) / ROWS;
    for (int tile = blockIdx.x; tile < ntiles; tile += gridDim.x) {
        int row0 = tile * ROWS;
        __syncthreads();
        {   // stage X tile (float4, padded rows, zero-fill tail)
            int base4 = row0 * (K / 4);
            int tot4 = nrows * (K / 4);
            for (int i = tid; i < ROWS * K / 4; i += 256) {
                float4 v = {0.f, 0.f, 0.f, 0.f};
                if (base4 + i < tot4) v = reinterpret_cast<const float4*>(X)[base4 + i];
                int rr = i / (K / 4), kk = i % (K / 4);
                *reinterpret_cast<float4*>(&Xl[rr * XSTR + kk * 4]) = v;
            }
        }
        __syncthreads();
        float4 acc[4];
#pragma unroll
        for (int rr = 0; rr < 4; ++rr)
            acc[rr] = *reinterpret_cast<const float4*>(&Bl[cg * 4]);
#pragma unroll 1
        for (int k = 0; k < K; k += 4) {
            const float4 w0 = *reinterpret_cast<const float4*>(&Wl[(k + 0) * M + cg * 4]);
            const float4 w1 = *reinterpret_cast<const float4*>(&Wl[(k + 1) * M + cg * 4]);
            const float4 w2 = *reinterpret_cast<const float4*>(&Wl[(k + 2) * M + cg * 4]);
            const float4 w3 = *reinterpret_cast<const float4*>(&Wl[(k + 3) * M + cg * 4]);
#pragma unroll
            for (int rr = 0; rr < 4; ++rr) {
                const float4 xv = *reinterpret_cast<const float4*>(
                    &Xl[(rg * 4 + rr) * XSTR + k]);
                acc[rr].x += xv.x * w0.x + xv.y * w1.x + xv.z * w2.x + xv.w * w3.x;
                acc[rr].y += xv.x * w0.y + xv.y * w1.y + xv.z * w2.y + xv.w * w3.y;
                acc[rr].z += xv.x * w0.z + xv.y * w1.z + xv.z * w2.z + xv.w * w3.z;
                acc[rr].w += xv.x * w0.w + xv.y * w1.w + xv.z * w2.w + xv.w * w3.w;
            }
        }
#pragma unroll
        for (int rr = 0; rr < 4; ++rr) {
            int row = row0 + rg * 4 + rr;
            if (row < nrows) {
                float4 a = acc[rr];
                if constexpr (RELU) {
                    a.x = fmaxf(a.x, 0.f); a.y = fmaxf(a.y, 0.f);
                    a.z = fmaxf(a.z, 0.f); a.w = fmaxf(a.w, 0.f);
                }
                if constexpr (SCALE) {
                    float d = dinv[row];
                    a.x *= d; a.y *= d; a.z *= d; a.w *= d;
                }
                *reinterpret_cast<float4*>(&Y[row * M + cg * 4]) = a;
            }
        }
    }
}

// h3 = relu(z3 + b3); pool sums/counts per graph.
// POOL_NPB 1024 -> 128: the old grid was 98 blocks on 256 CUs (4% occupancy,
// 256 serial latency-exposed iterations per wave -> 91 us hidden for 16
// rounds). Now 782 blocks (~12 waves/CU), each wave a CONTIGUOUS 32-node
// run (fewest graph-boundary flushes). Atomics ~400K over 16K addresses --
// ~24/address, far from the R1 serialization regime.
#define POOL_NPB 128   // nodes per block (32 per wave, contiguous)
__global__ __launch_bounds__(256) void pool_kernel(
        const float* __restrict__ z3, const float* __restrict__ b3,
        const int* __restrict__ batch, float* __restrict__ sums,
        float* __restrict__ cntf, int n) {
    int wave = threadIdx.x >> 6;
    int lane = threadIdx.x & 63;   // feature index
    int node0 = blockIdx.x * POOL_NPB + wave * 32;
    int nodeEnd = min(node0 + 32, n);
    if (node0 >= n) return;
    float bias = b3[lane];
    float acc = 0.0f, cnt = 0.0f;
    int curg = -1;
    for (int node = node0; node < nodeEnd; ++node) {
        int g = batch[node];               // wave-uniform (lane = feature)
        if (g != curg) {                   // wave-uniform branch
            if (curg >= 0) {
                atomicAdd(&sums[curg * 64 + lane], acc);
                if (lane == 0) atomicAdd(&cntf[curg], cnt);
            }
            curg = g; acc = 0.0f; cnt = 0.0f;
        }
        acc += fmaxf(__builtin_nontemporal_load(&z3[node * 64 + lane]) + bias, 0.0f);
        cnt += 1.0f;
    }
    if (curg >= 0) {
        atomicAdd(&sums[curg * 64 + lane], acc);
        if (lane == 0) atomicAdd(&cntf[curg], cnt);
    }
}

// per-graph: g = sums/max(cnt,1); hid = relu(g@Wl1+bl1); out = hid@Wl2+bl2
__global__ void mlp_kernel(const float* __restrict__ sums, const float* __restrict__ cntf,
                           const float* __restrict__ Wl1, const float* __restrict__ bl1,
                           const float* __restrict__ Wl2, const float* __restrict__ bl2,
                           float* __restrict__ out) {
    __shared__ float gv[64];
    __shared__ float hid[32];
    int g = blockIdx.x, t = threadIdx.x;
    float denom = fmaxf(cntf[g], 1.0f);
    gv[t] = sums[g * 64 + t] / denom;
    __syncthreads();
    if (t < 32) {
        float a = bl1[t];
#pragma unroll
        for (int k = 0; k < 64; ++k) a += gv[k] * Wl1[k * 32 + t];
        hid[t] = fmaxf(a, 0.0f);
    }
    __syncthreads();
    if (t == 0) {
        float o = bl2[0];
#pragma unroll
        for (int k = 0; k < 32; ++k) o += hid[k] * Wl2[k];
        out[g] = o;
    }
}

extern "C" void kernel_launch(void* const* d_in, const int* in_sizes, int n_in,
                              void* d_out, int out_size, void* d_ws, size_t ws_size,
                              hipStream_t stream) {
    const float* x   = (const float*)d_in[0];
    const int* ei    = (const int*)d_in[1];
    const int* batch = (const int*)d_in[2];
    const float* W1  = (const float*)d_in[3];
    const float* b1  = (const float*)d_in[4];
    const float* W2  = (const float*)d_in[5];
    const float* b2  = (const float*)d_in[6];
    const float* W3  = (const float*)d_in[7];
    const float* b3  = (const float*)d_in[8];
    const float* Wl1 = (const float*)d_in[9];
    const float* bl1 = (const float*)d_in[10];
    const float* Wl2 = (const float*)d_in[11];
    const float* bl2 = (const float*)d_in[12];
    float* out = (float*)d_out;

    const int N = N_NODES;
    const int E = in_sizes[1] / 2;   // 3.2M
    const int* src = ei;
    const int* dst = ei + E;

    char* ws = (char*)d_ws;
    float* sums    = (float*)(ws + OFF_SUMS);
    float* cntf    = (float*)(ws + OFF_CNTF);
    int*   hist    = (int*)(ws + OFF_HIST);
    int*   bsum    = (int*)(ws + OFF_BSUM);
    int*   row_ptr = (int*)(ws + OFF_ROWPTR);
    float* dinv    = (float*)(ws + OFF_DINV);
    int*   col     = (int*)(ws + OFF_COL);
    float* xs1     = (float*)(ws + OFF_XS1);
    float* bufQ    = (float*)(ws + OFF_BUFQ);   // xs2, later z3
    float* bufR    = (float*)(ws + OFF_BUFR);   // z2, later ys
    float* bufP    = (float*)(ws + OFF_BUFP);   // h2
    int*   packed  = (int*)(ws + OFF_PAIRS);    // aliases bufP (dead before h2)

    // CSR build: hist(+zero) -> scanA -> bin -> csr(+xs1 scale)
    int epb = (E + NBLK - 1) / NBLK;   // 12500
    hist_kernel<<<NBLK, 256, 0, stream>>>(dst, hist, (int*)ws, E, epb);
    scanhA_kernel<<<SCAN_BLKS, 1024, 0, stream>>>(hist, bsum);
    bin_kernel<<<NBLK, 256, 0, stream>>>(src, dst, hist, bsum, packed, E, epb);
    csr_kernel<<<NB_BUCKETS, 512, 0, stream>>>(packed, hist, bsum, x,
                                               row_ptr, dinv, xs1, col, E);

    // Layer 1 (agg + gemm1 fused): xs2 = dinv*relu((agg xs1)@W1+b1)
    agg8g1_kernel<<<(N + 3) / 4, 256, 0, stream>>>(xs1, row_ptr, col, dinv, W1, b1, bufQ, N);

    // Layer 2: z2 = agg(xs2) [split halves] ; h2 = relu(z2@W2+b2)
    const int HALF = N / 2;   // 50000
    agg64_kernel<<<(HALF + 3) / 4, 256, 0, stream>>>(bufQ, row_ptr, col, dinv, bufR, 0, HALF);
    agg64_kernel<<<(N - HALF + 3) / 4, 256, 0, stream>>>(bufQ, row_ptr, col, dinv, bufR, HALF, N);
    gemm_kernel<64, 128, true, true, false><<<3125, 256, 0, stream>>>(bufR, W2, b2, nullptr, bufP, N);

    // Layer 3: ys = dinv*(h2@W3) ; z3 = agg(ys) [split halves]
    gemm_kernel<128, 64, false, false, true><<<1563, 256, 0, stream>>>(bufP, W3, nullptr, dinv, bufR, N);
    agg64_kernel<<<(HALF + 3) / 4, 256, 0, stream>>>(bufR, row_ptr, col, dinv, bufQ, 0, HALF);
    agg64_kernel<<<(N - HALF + 3) / 4, 256, 0, stream>>>(bufR, row_ptr, col, dinv, bufQ, HALF, N);

    // Pool + MLP head
    pool_kernel<<<(N + POOL_NPB - 1) / POOL_NPB, 256, 0, stream>>>(bufQ, b3, batch, sums, cntf, N);
    mlp_kernel<<<N_GRAPHS, 64, 0, stream>>>(sums, cntf, Wl1, bl1, Wl2, bl2, out);
}

// Round 19
// 507.420 us; speedup vs baseline: 1.1615x; 1.0241x over previous
//
#include <hip/hip_runtime.h>
#include <hip/hip_bf16.h>

#define N_NODES 100000
#define N_EDGES 3200000
#define N_GRAPHS 256
#define NB_BUCKETS 196      // ceil(100000 / 512)
#define BSHIFT 9            // 512 nodes per bucket
#define NBLK 256            // blocks for hist/bin passes
#define SCAN_BLKS 49        // 50176 / 1024
#define CSR_CAP 22528       // LDS staging capacity (88 KB); avg bucket 16.4K edges

// ---------------- workspace layout (bytes) ----------------
#define OFF_SUMS      0u            // float[256*64] pool sums (zeroed in hist)
#define OFF_CNTF      65536u        // float[256] pool counts (zeroed in hist)
#define ZERO_BYTES    66560u
#define OFF_HIST      66560u        // int[196*256] (bucket-major) per-(bucket,block) counts
#define OFF_BSUM      267264u       // int[64] scan block sums
#define OFF_ROWPTR    267776u       // int[N+1]
#define OFF_DINV      668160u       // float[N]
#define OFF_COL       1068544u      // int[E]
#define OFF_XS1       13868544u     // float[N*8]
#define OFF_BUFQ      20268544u     // float[N*64]  xs2, later z3
#define OFF_BUFR      45868544u     // float[N*64]  z2, later ys
#define OFF_BUFP      71468544u     // float[N*128] h2; ALIASED: packed[E] (dead before h2)
#define OFF_PAIRS     OFF_BUFP
// total ~122.7 MB (proven through R18)

// ---- P1: per-(bucket,block) histogram of dst. Also zeroes the pool
// accumulators (was a separate zero_kernel dispatch).
__global__ __launch_bounds__(256) void hist_kernel(const int* __restrict__ dst,
                                                   int* __restrict__ hist,
                                                   int* __restrict__ zbase,
                                                   int E, int epb) {
    __shared__ int h[NB_BUCKETS];
    int t = threadIdx.x, blk = blockIdx.x;
    int gid = blk * 256 + t;
    if (gid < (int)(ZERO_BYTES / 4)) zbase[gid] = 0;
    if (t < NB_BUCKETS) h[t] = 0;
    __syncthreads();
    int e0 = blk * epb, e1 = min(e0 + epb, E);
    for (int e = e0 + t; e < e1; e += 256)
        atomicAdd(&h[__builtin_nontemporal_load(&dst[e]) >> BSHIFT], 1);
    __syncthreads();
    if (t < NB_BUCKETS) hist[t * NBLK + blk] = h[t];
}

// ---- P2: block-local exclusive scan of hist[50176] + per-block sums.
__global__ __launch_bounds__(1024) void scanhA_kernel(int* __restrict__ hist,
                                                      int* __restrict__ bsum) {
    __shared__ int s[1024];
    int t = threadIdx.x;
    int i = blockIdx.x * 1024 + t;     // 49*1024 == 50176 exactly
    int v = hist[i];
    s[t] = v;
    __syncthreads();
    for (int off = 1; off < 1024; off <<= 1) {
        int add = (t >= off) ? s[t - off] : 0;
        __syncthreads();
        s[t] += add;
        __syncthreads();
    }
    hist[i] = s[t] - v;                // block-local exclusive
    if (t == 1023) bsum[blockIdx.x] = s[t];
}

// ---- P3: bin edges, PACKED (dl<<17 | src), local offset scan.
__global__ __launch_bounds__(256) void bin_kernel(const int* __restrict__ src,
                                                  const int* __restrict__ dst,
                                                  const int* __restrict__ hist,
                                                  const int* __restrict__ bsum,
                                                  int* __restrict__ packed, int E, int epb) {
    __shared__ int cur[NB_BUCKETS];
    __shared__ int boffL[SCAN_BLKS];
    int t = threadIdx.x, blk = blockIdx.x;
    if (t < 64) {
        int orig = (t < SCAN_BLKS) ? bsum[t] : 0;
        int v = orig;
        for (int off = 1; off < 64; off <<= 1) {
            int up = __shfl_up(v, off);
            if (t >= off) v += up;
        }
        if (t < SCAN_BLKS) boffL[t] = v - orig;   // exclusive
    }
    __syncthreads();
    if (t < NB_BUCKETS) {
        int i = t * NBLK + blk;
        cur[t] = hist[i] + boffL[i >> 10];
    }
    __syncthreads();
    int e0 = blk * epb, e1 = min(e0 + epb, E);
    for (int e = e0 + t; e < e1; e += 256) {
        int d = __builtin_nontemporal_load(&dst[e]);
        int sv = __builtin_nontemporal_load(&src[e]);
        int pos = atomicAdd(&cur[d >> BSHIFT], 1);
        packed[pos] = ((d & 511) << 17) | sv;
    }
}

// ---- P4: per-bucket CSR finalize + xs1 = dinv*x.
// col scatter now STAGED IN LDS: the bucket's output is a contiguous
// [start,end) permutation, so build it in an 88 KB LDS buffer (random-bank
// LDS writes are cheap) and stream out with coalesced full-line stores --
// was 3.2M scattered global dword stores (~50 L2 transactions per wave).
// Overflow (>CSR_CAP edges, ~13 sigma) falls back to direct stores.
__global__ __launch_bounds__(512) void csr_kernel(const int* __restrict__ packed,
                                                  const int* __restrict__ hist,
                                                  const int* __restrict__ bsum,
                                                  const float* __restrict__ x,
                                                  int* __restrict__ row_ptr,
                                                  float* __restrict__ dinv,
                                                  float* __restrict__ xs1,
                                                  int* __restrict__ col, int E) {
    __shared__ int cntL[512];
    __shared__ int rsL[512];
    __shared__ int fillL[512];
    __shared__ int boffL[SCAN_BLKS];
    __shared__ int srcL[CSR_CAP];   // 88 KB staging
    int t = threadIdx.x, b = blockIdx.x;
    int lo = b << BSHIFT;
    int nloc = min(512, N_NODES - lo);
    cntL[t] = 0;
    fillL[t] = 0;
    if (t < 64) {
        int orig = (t < SCAN_BLKS) ? bsum[t] : 0;
        int v = orig;
        for (int off = 1; off < 64; off <<= 1) {
            int up = __shfl_up(v, off);
            if (t >= off) v += up;
        }
        if (t < SCAN_BLKS) boffL[t] = v - orig;   // exclusive
    }
    __syncthreads();
    int i0 = b * NBLK;
    int start = hist[i0] + boffL[i0 >> 10];
    int end;
    if (b == NB_BUCKETS - 1) end = E;
    else {
        int i1 = (b + 1) * NBLK;
        end = hist[i1] + boffL[i1 >> 10];
    }
    for (int e = start + t; e < end; e += 512)
        atomicAdd(&cntL[packed[e] >> 17], 1);
    __syncthreads();
    int v = cntL[t];
    __syncthreads();
    for (int off = 1; off < 512; off <<= 1) {     // inclusive scan (Hillis-Steele)
        int add = (t >= off) ? cntL[t - off] : 0;
        __syncthreads();
        cntL[t] += add;
        __syncthreads();
    }
    int rowstart = start + cntL[t] - v;           // exclusive + bucket base
    rsL[t] = rowstart;
    if (t < nloc) {
        int node = lo + t;
        row_ptr[node] = rowstart;
        float d = rsqrtf((float)(v + 1));
        dinv[node] = d;
        const float4* xv = reinterpret_cast<const float4*>(x) + node * 2;
        float4 xa = xv[0], xb = xv[1];
        xa.x *= d; xa.y *= d; xa.z *= d; xa.w *= d;
        xb.x *= d; xb.y *= d; xb.z *= d; xb.w *= d;
        float4* xo = reinterpret_cast<float4*>(xs1) + node * 2;
        xo[0] = xa; xo[1] = xb;
    }
    if (b == NB_BUCKETS - 1 && t == 0) row_ptr[N_NODES] = E;
    __syncthreads();
    for (int e = start + t; e < end; e += 512) {
        int p = packed[e];
        int dl = p >> 17;
        int pos = rsL[dl] + atomicAdd(&fillL[dl], 1);
        int rel = pos - start;
        if (rel < CSR_CAP) srcL[rel] = p & 0x1FFFF;
        else col[pos] = p & 0x1FFFF;          // overflow fallback
    }
    __syncthreads();
    int lim = min(end - start, CSR_CAP);
    for (int i = t; i < lim; i += 512)
        col[start + i] = srcL[i];             // coalesced write-out
}

// Layer-1 aggregation FUSED with gemm1 (proven R13 form).
__global__ __launch_bounds__(256) void agg8g1_kernel(
        const float* __restrict__ xs, const int* __restrict__ row_ptr,
        const int* __restrict__ col, const float* __restrict__ dinv,
        const float* __restrict__ W1, const float* __restrict__ b1,
        float* __restrict__ xs2, int n) {
    int wave = threadIdx.x >> 6;            // 4 waves/block = 4 nodes/block
    int node = blockIdx.x * 4 + wave;
    if (node >= n) return;
    int lane = threadIdx.x & 63;
    int j = lane >> 1, l = lane & 1;
    int e0 = row_ptr[node], e1 = row_ptr[node + 1];
    float4 acc0 = {0.f, 0.f, 0.f, 0.f}, acc1 = acc0;
    if (j == 0) {   // self-loop term, counted once (2 lanes, one per half)
        const float4 sv = *reinterpret_cast<const float4*>(&xs[node * 8 + 4 * l]);
        acc0.x += sv.x; acc0.y += sv.y; acc0.z += sv.z; acc0.w += sv.w;
    }
    int base = e0;
    for (; base + 64 <= e1; base += 64) {   // 64 edges per iteration
        int s0 = __builtin_nontemporal_load(&col[base + j]);
        int s1 = __builtin_nontemporal_load(&col[base + 32 + j]);
        const float4 v0 = *reinterpret_cast<const float4*>(&xs[s0 * 8 + 4 * l]);
        const float4 v1 = *reinterpret_cast<const float4*>(&xs[s1 * 8 + 4 * l]);
        acc0.x += v0.x; acc0.y += v0.y; acc0.z += v0.z; acc0.w += v0.w;
        acc1.x += v1.x; acc1.y += v1.y; acc1.z += v1.z; acc1.w += v1.w;
    }
    if (base < e1) {                        // single masked pass (<=63 edges)
        int ee0 = base + j;
        int ee1 = base + 32 + j;
        int s0 = __builtin_nontemporal_load(&col[min(ee0, e1 - 1)]);
        int s1 = __builtin_nontemporal_load(&col[min(ee1, e1 - 1)]);
        float m0 = (ee0 < e1) ? 1.0f : 0.0f;
        float m1 = (ee1 < e1) ? 1.0f : 0.0f;
        const float4 v0 = *reinterpret_cast<const float4*>(&xs[s0 * 8 + 4 * l]);
        const float4 v1 = *reinterpret_cast<const float4*>(&xs[s1 * 8 + 4 * l]);
        acc0.x += m0 * v0.x; acc0.y += m0 * v0.y; acc0.z += m0 * v0.z; acc0.w += m0 * v0.w;
        acc1.x += m1 * v1.x; acc1.y += m1 * v1.y; acc1.z += m1 * v1.z; acc1.w += m1 * v1.w;
    }
    float4 r;
    r.x = acc0.x + acc1.x; r.y = acc0.y + acc1.y;
    r.z = acc0.z + acc1.z; r.w = acc0.w + acc1.w;
    r.x += __shfl_xor(r.x, 2);  r.y += __shfl_xor(r.y, 2);
    r.z += __shfl_xor(r.z, 2);  r.w += __shfl_xor(r.w, 2);
    r.x += __shfl_xor(r.x, 4);  r.y += __shfl_xor(r.y, 4);
    r.z += __shfl_xor(r.z, 4);  r.w += __shfl_xor(r.w, 4);
    r.x += __shfl_xor(r.x, 8);  r.y += __shfl_xor(r.y, 8);
    r.z += __shfl_xor(r.z, 8);  r.w += __shfl_xor(r.w, 8);
    r.x += __shfl_xor(r.x, 16); r.y += __shfl_xor(r.y, 16);
    r.z += __shfl_xor(r.z, 16); r.w += __shfl_xor(r.w, 16);
    r.x += __shfl_xor(r.x, 32); r.y += __shfl_xor(r.y, 32);
    r.z += __shfl_xor(r.z, 32); r.w += __shfl_xor(r.w, 32);
    float d = dinv[node];
    r.x *= d; r.y *= d; r.z *= d; r.w *= d;
    float z10 = __shfl(r.x, 0), z11 = __shfl(r.y, 0);
    float z12 = __shfl(r.z, 0), z13 = __shfl(r.w, 0);
    float z14 = __shfl(r.x, 1), z15 = __shfl(r.y, 1);
    float z16 = __shfl(r.z, 1), z17 = __shfl(r.w, 1);
    float a = b1[lane];
    a += z10 * W1[0 * 64 + lane];
    a += z11 * W1[1 * 64 + lane];
    a += z12 * W1[2 * 64 + lane];
    a += z13 * W1[3 * 64 + lane];
    a += z14 * W1[4 * 64 + lane];
    a += z15 * W1[5 * 64 + lane];
    a += z16 * W1[6 * 64 + lane];
    a += z17 * W1[7 * 64 + lane];
    xs2[node * 64 + lane] = d * fmaxf(a, 0.0f);
}

// D=64 aggregation, float4-per-lane gather, batched masked remainder.
// Layer-2 call is merged (one dispatch); layer-3 stays split in halves so
// top-5 slots 4-5 keep measuring the largest mid-tier kernels.
__global__ __launch_bounds__(256) void agg64_kernel(
        const float* __restrict__ xs, const int* __restrict__ row_ptr,
        const int* __restrict__ col, const float* __restrict__ dinv,
        float* __restrict__ z, int node0, int nend) {
    int wave = threadIdx.x >> 6;            // 4 waves/block = 4 nodes/block
    int node = node0 + blockIdx.x * 4 + wave;
    if (node >= nend) return;
    int lane = threadIdx.x & 63;
    int j = lane >> 4, l = lane & 15;
    int e0 = row_ptr[node], e1 = row_ptr[node + 1];
    float4 acc0 = {0.f, 0.f, 0.f, 0.f}, acc1 = acc0, acc2 = acc0, acc3 = acc0;
    if (j == 0) {   // self-loop term, counted once
        const float4 sv = *reinterpret_cast<const float4*>(&xs[node * 64 + 4 * l]);
        acc0.x += sv.x; acc0.y += sv.y; acc0.z += sv.z; acc0.w += sv.w;
    }
    int base = e0;
    for (; base + 32 <= e1; base += 32) {   // 32 edges per iteration
        int s0 = __builtin_nontemporal_load(&col[base + j]);
        int s1 = __builtin_nontemporal_load(&col[base + 4 + j]);
        int s2 = __builtin_nontemporal_load(&col[base + 8 + j]);
        int s3 = __builtin_nontemporal_load(&col[base + 12 + j]);
        int s4 = __builtin_nontemporal_load(&col[base + 16 + j]);
        int s5 = __builtin_nontemporal_load(&col[base + 20 + j]);
        int s6 = __builtin_nontemporal_load(&col[base + 24 + j]);
        int s7 = __builtin_nontemporal_load(&col[base + 28 + j]);
        const float4 v0 = *reinterpret_cast<const float4*>(&xs[s0 * 64 + 4 * l]);
        const float4 v1 = *reinterpret_cast<const float4*>(&xs[s1 * 64 + 4 * l]);
        const float4 v2 = *reinterpret_cast<const float4*>(&xs[s2 * 64 + 4 * l]);
        const float4 v3 = *reinterpret_cast<const float4*>(&xs[s3 * 64 + 4 * l]);
        const float4 v4 = *reinterpret_cast<const float4*>(&xs[s4 * 64 + 4 * l]);
        const float4 v5 = *reinterpret_cast<const float4*>(&xs[s5 * 64 + 4 * l]);
        const float4 v6 = *reinterpret_cast<const float4*>(&xs[s6 * 64 + 4 * l]);
        const float4 v7 = *reinterpret_cast<const float4*>(&xs[s7 * 64 + 4 * l]);
        acc0.x += v0.x; acc0.y += v0.y; acc0.z += v0.z; acc0.w += v0.w;
        acc1.x += v1.x; acc1.y += v1.y; acc1.z += v1.z; acc1.w += v1.w;
        acc2.x += v2.x; acc2.y += v2.y; acc2.z += v2.z; acc2.w += v2.w;
        acc3.x += v3.x; acc3.y += v3.y; acc3.z += v3.z; acc3.w += v3.w;
        acc0.x += v4.x; acc0.y += v4.y; acc0.z += v4.z; acc0.w += v4.w;
        acc1.x += v5.x; acc1.y += v5.y; acc1.z += v5.z; acc1.w += v5.w;
        acc2.x += v6.x; acc2.y += v6.y; acc2.z += v6.z; acc2.w += v6.w;
        acc3.x += v7.x; acc3.y += v7.y; acc3.z += v7.z; acc3.w += v7.w;
    }
    if (base < e1) {   // single masked pass for <=31 remaining edges
        int ee0 = base + j,      ee1 = base + 4 + j;
        int ee2 = base + 8 + j,  ee3 = base + 12 + j;
        int ee4 = base + 16 + j, ee5 = base + 20 + j;
        int ee6 = base + 24 + j, ee7 = base + 28 + j;
        int s0 = __builtin_nontemporal_load(&col[min(ee0, e1 - 1)]);
        int s1 = __builtin_nontemporal_load(&col[min(ee1, e1 - 1)]);
        int s2 = __builtin_nontemporal_load(&col[min(ee2, e1 - 1)]);
        int s3 = __builtin_nontemporal_load(&col[min(ee3, e1 - 1)]);
        int s4 = __builtin_nontemporal_load(&col[min(ee4, e1 - 1)]);
        int s5 = __builtin_nontemporal_load(&col[min(ee5, e1 - 1)]);
        int s6 = __builtin_nontemporal_load(&col[min(ee6, e1 - 1)]);
        int s7 = __builtin_nontemporal_load(&col[min(ee7, e1 - 1)]);
        float m0 = (ee0 < e1) ? 1.f : 0.f, m1 = (ee1 < e1) ? 1.f : 0.f;
        float m2 = (ee2 < e1) ? 1.f : 0.f, m3 = (ee3 < e1) ? 1.f : 0.f;
        float m4 = (ee4 < e1) ? 1.f : 0.f, m5 = (ee5 < e1) ? 1.f : 0.f;
        float m6 = (ee6 < e1) ? 1.f : 0.f, m7 = (ee7 < e1) ? 1.f : 0.f;
        const float4 v0 = *reinterpret_cast<const float4*>(&xs[s0 * 64 + 4 * l]);
        const float4 v1 = *reinterpret_cast<const float4*>(&xs[s1 * 64 + 4 * l]);
        const float4 v2 = *reinterpret_cast<const float4*>(&xs[s2 * 64 + 4 * l]);
        const float4 v3 = *reinterpret_cast<const float4*>(&xs[s3 * 64 + 4 * l]);
        const float4 v4 = *reinterpret_cast<const float4*>(&xs[s4 * 64 + 4 * l]);
        const float4 v5 = *reinterpret_cast<const float4*>(&xs[s5 * 64 + 4 * l]);
        const float4 v6 = *reinterpret_cast<const float4*>(&xs[s6 * 64 + 4 * l]);
        const float4 v7 = *reinterpret_cast<const float4*>(&xs[s7 * 64 + 4 * l]);
        acc0.x += m0 * v0.x; acc0.y += m0 * v0.y; acc0.z += m0 * v0.z; acc0.w += m0 * v0.w;
        acc1.x += m1 * v1.x; acc1.y += m1 * v1.y; acc1.z += m1 * v1.z; acc1.w += m1 * v1.w;
        acc2.x += m2 * v2.x; acc2.y += m2 * v2.y; acc2.z += m2 * v2.z; acc2.w += m2 * v2.w;
        acc3.x += m3 * v3.x; acc3.y += m3 * v3.y; acc3.z += m3 * v3.z; acc3.w += m3 * v3.w;
        acc0.x += m4 * v4.x; acc0.y += m4 * v4.y; acc0.z += m4 * v4.z; acc0.w += m4 * v4.w;
        acc1.x += m5 * v5.x; acc1.y += m5 * v5.y; acc1.z += m5 * v5.z; acc1.w += m5 * v5.w;
        acc2.x += m6 * v6.x; acc2.y += m6 * v6.y; acc2.z += m6 * v6.z; acc2.w += m6 * v6.w;
        acc3.x += m7 * v7.x; acc3.y += m7 * v7.y; acc3.z += m7 * v7.z; acc3.w += m7 * v7.w;
    }
    float4 r;
    r.x = (acc0.x + acc1.x) + (acc2.x + acc3.x);
    r.y = (acc0.y + acc1.y) + (acc2.y + acc3.y);
    r.z = (acc0.z + acc1.z) + (acc2.z + acc3.z);
    r.w = (acc0.w + acc1.w) + (acc2.w + acc3.w);
    r.x += __shfl_xor(r.x, 16); r.y += __shfl_xor(r.y, 16);
    r.z += __shfl_xor(r.z, 16); r.w += __shfl_xor(r.w, 16);
    r.x += __shfl_xor(r.x, 32); r.y += __shfl_xor(r.y, 32);
    r.z += __shfl_xor(r.z, 32); r.w += __shfl_xor(r.w, 32);
    if (j == 0) {
        float d = dinv[node];
        r.x *= d; r.y *= d; r.z *= d; r.w *= d;
        *reinterpret_cast<float4*>(&z[node * 64 + 4 * l]) = r;
    }
}

// Y[row, :] = opt_scale(dinv[row]) * opt_relu( X[row,:] @ W + opt_bias )
// Register-blocked 4x4, bounded unroll (R16 proven form).
template <int K, int M, bool BIAS, bool RELU, bool SCALE>
__global__ __launch_bounds__(256) void gemm_kernel(
        const float* __restrict__ X, const float* __restrict__ W,
        const float* __restrict__ b, const float* __restrict__ dinv,
        float* __restrict__ Y, int nrows) {
    constexpr int CG = M / 4;          // col-groups (gemm2: 32, gemm3: 16)
    constexpr int RG = 256 / CG;       // row-groups  (gemm2: 8,  gemm3: 16)
    constexpr int ROWS = RG * 4;       // rows/tile   (gemm2: 32, gemm3: 64)
    constexpr int XSTR = K + 4;        // padded X stride (bank decorrelation)
    __shared__ float Wl[K * M];        // 32 KB
    __shared__ float Xl[ROWS * XSTR];
    __shared__ float Bl[M];
    int tid = threadIdx.x;
    {   // float4 weight staging
        const float4* Wv = reinterpret_cast<const float4*>(W);
        float4* Wlv = reinterpret_cast<float4*>(Wl);
        for (int i = tid; i < K * M / 4; i += 256) Wlv[i] = Wv[i];
    }
    if (tid < M) Bl[tid] = BIAS ? b[tid] : 0.0f;
    int cg = tid % CG;
    int rg = tid / CG;
    int ntiles = (nrows + ROWS - 1) / ROWS;
    for (int tile = blockIdx.x; tile < ntiles; tile += gridDim.x) {
        int row0 = tile * ROWS;
        __syncthreads();
        {   // stage X tile (float4, padded rows, zero-fill tail)
            int base4 = row0 * (K / 4);
            int tot4 = nrows * (K / 4);
            for (int i = tid; i < ROWS * K / 4; i += 256) {
                float4 v = {0.f, 0.f, 0.f, 0.f};
                if (base4 + i < tot4) v = reinterpret_cast<const float4*>(X)[base4 + i];
                int rr = i / (K / 4), kk = i % (K / 4);
                *reinterpret_cast<float4*>(&Xl[rr * XSTR + kk * 4]) = v;
            }
        }
        __syncthreads();
        float4 acc[4];
#pragma unroll
        for (int rr = 0; rr < 4; ++rr)
            acc[rr] = *reinterpret_cast<const float4*>(&Bl[cg * 4]);
#pragma unroll 1
        for (int k = 0; k < K; k += 4) {
            const float4 w0 = *reinterpret_cast<const float4*>(&Wl[(k + 0) * M + cg * 4]);
            const float4 w1 = *reinterpret_cast<const float4*>(&Wl[(k + 1) * M + cg * 4]);
            const float4 w2 = *reinterpret_cast<const float4*>(&Wl[(k + 2) * M + cg * 4]);
            const float4 w3 = *reinterpret_cast<const float4*>(&Wl[(k + 3) * M + cg * 4]);
#pragma unroll
            for (int rr = 0; rr < 4; ++rr) {
                const float4 xv = *reinterpret_cast<const float4*>(
                    &Xl[(rg * 4 + rr) * XSTR + k]);
                acc[rr].x += xv.x * w0.x + xv.y * w1.x + xv.z * w2.x + xv.w * w3.x;
                acc[rr].y += xv.x * w0.y + xv.y * w1.y + xv.z * w2.y + xv.w * w3.y;
                acc[rr].z += xv.x * w0.z + xv.y * w1.z + xv.z * w2.z + xv.w * w3.z;
                acc[rr].w += xv.x * w0.w + xv.y * w1.w + xv.z * w2.w + xv.w * w3.w;
            }
        }
#pragma unroll
        for (int rr = 0; rr < 4; ++rr) {
            int row = row0 + rg * 4 + rr;
            if (row < nrows) {
                float4 a = acc[rr];
                if constexpr (RELU) {
                    a.x = fmaxf(a.x, 0.f); a.y = fmaxf(a.y, 0.f);
                    a.z = fmaxf(a.z, 0.f); a.w = fmaxf(a.w, 0.f);
                }
                if constexpr (SCALE) {
                    float d = dinv[row];
                    a.x *= d; a.y *= d; a.z *= d; a.w *= d;
                }
                *reinterpret_cast<float4*>(&Y[row * M + cg * 4]) = a;
            }
        }
    }
}

// h3 = relu(z3 + b3); pool sums/counts per graph (R18 proven form:
// 782 blocks, contiguous 32-node runs per wave).
#define POOL_NPB 128   // nodes per block (32 per wave, contiguous)
__global__ __launch_bounds__(256) void pool_kernel(
        const float* __restrict__ z3, const float* __restrict__ b3,
        const int* __restrict__ batch, float* __restrict__ sums,
        float* __restrict__ cntf, int n) {
    int wave = threadIdx.x >> 6;
    int lane = threadIdx.x & 63;   // feature index
    int node0 = blockIdx.x * POOL_NPB + wave * 32;
    int nodeEnd = min(node0 + 32, n);
    if (node0 >= n) return;
    float bias = b3[lane];
    float acc = 0.0f, cnt = 0.0f;
    int curg = -1;
    for (int node = node0; node < nodeEnd; ++node) {
        int g = batch[node];               // wave-uniform (lane = feature)
        if (g != curg) {                   // wave-uniform branch
            if (curg >= 0) {
                atomicAdd(&sums[curg * 64 + lane], acc);
                if (lane == 0) atomicAdd(&cntf[curg], cnt);
            }
            curg = g; acc = 0.0f; cnt = 0.0f;
        }
        acc += fmaxf(__builtin_nontemporal_load(&z3[node * 64 + lane]) + bias, 0.0f);
        cnt += 1.0f;
    }
    if (curg >= 0) {
        atomicAdd(&sums[curg * 64 + lane], acc);
        if (lane == 0) atomicAdd(&cntf[curg], cnt);
    }
}

// per-graph: g = sums/max(cnt,1); hid = relu(g@Wl1+bl1); out = hid@Wl2+bl2
__global__ void mlp_kernel(const float* __restrict__ sums, const float* __restrict__ cntf,
                           const float* __restrict__ Wl1, const float* __restrict__ bl1,
                           const float* __restrict__ Wl2, const float* __restrict__ bl2,
                           float* __restrict__ out) {
    __shared__ float gv[64];
    __shared__ float hid[32];
    int g = blockIdx.x, t = threadIdx.x;
    float denom = fmaxf(cntf[g], 1.0f);
    gv[t] = sums[g * 64 + t] / denom;
    __syncthreads();
    if (t < 32) {
        float a = bl1[t];
#pragma unroll
        for (int k = 0; k < 64; ++k) a += gv[k] * Wl1[k * 32 + t];
        hid[t] = fmaxf(a, 0.0f);
    }
    __syncthreads();
    if (t == 0) {
        float o = bl2[0];
#pragma unroll
        for (int k = 0; k < 32; ++k) o += hid[k] * Wl2[k];
        out[g] = o;
    }
}

extern "C" void kernel_launch(void* const* d_in, const int* in_sizes, int n_in,
                              void* d_out, int out_size, void* d_ws, size_t ws_size,
                              hipStream_t stream) {
    const float* x   = (const float*)d_in[0];
    const int* ei    = (const int*)d_in[1];
    const int* batch = (const int*)d_in[2];
    const float* W1  = (const float*)d_in[3];
    const float* b1  = (const float*)d_in[4];
    const float* W2  = (const float*)d_in[5];
    const float* b2  = (const float*)d_in[6];
    const float* W3  = (const float*)d_in[7];
    const float* b3  = (const float*)d_in[8];
    const float* Wl1 = (const float*)d_in[9];
    const float* bl1 = (const float*)d_in[10];
    const float* Wl2 = (const float*)d_in[11];
    const float* bl2 = (const float*)d_in[12];
    float* out = (float*)d_out;

    const int N = N_NODES;
    const int E = in_sizes[1] / 2;   // 3.2M
    const int* src = ei;
    const int* dst = ei + E;

    char* ws = (char*)d_ws;
    float* sums    = (float*)(ws + OFF_SUMS);
    float* cntf    = (float*)(ws + OFF_CNTF);
    int*   hist    = (int*)(ws + OFF_HIST);
    int*   bsum    = (int*)(ws + OFF_BSUM);
    int*   row_ptr = (int*)(ws + OFF_ROWPTR);
    float* dinv    = (float*)(ws + OFF_DINV);
    int*   col     = (int*)(ws + OFF_COL);
    float* xs1     = (float*)(ws + OFF_XS1);
    float* bufQ    = (float*)(ws + OFF_BUFQ);   // xs2, later z3
    float* bufR    = (float*)(ws + OFF_BUFR);   // z2, later ys
    float* bufP    = (float*)(ws + OFF_BUFP);   // h2
    int*   packed  = (int*)(ws + OFF_PAIRS);    // aliases bufP (dead before h2)

    // CSR build: hist(+zero) -> scanA -> bin -> csr(+xs1 scale, LDS-staged col)
    int epb = (E + NBLK - 1) / NBLK;   // 12500
    hist_kernel<<<NBLK, 256, 0, stream>>>(dst, hist, (int*)ws, E, epb);
    scanhA_kernel<<<SCAN_BLKS, 1024, 0, stream>>>(hist, bsum);
    bin_kernel<<<NBLK, 256, 0, stream>>>(src, dst, hist, bsum, packed, E, epb);
    csr_kernel<<<NB_BUCKETS, 512, 0, stream>>>(packed, hist, bsum, x,
                                               row_ptr, dinv, xs1, col, E);

    // Layer 1 (agg + gemm1 fused): xs2 = dinv*relu((agg xs1)@W1+b1)
    agg8g1_kernel<<<(N + 3) / 4, 256, 0, stream>>>(xs1, row_ptr, col, dinv, W1, b1, bufQ, N);

    // Layer 2: z2 = agg(xs2) [merged] ; h2 = relu(z2@W2+b2)
    agg64_kernel<<<(N + 3) / 4, 256, 0, stream>>>(bufQ, row_ptr, col, dinv, bufR, 0, N);
    gemm_kernel<64, 128, true, true, false><<<3125, 256, 0, stream>>>(bufR, W2, b2, nullptr, bufP, N);

    // Layer 3: ys = dinv*(h2@W3) ; z3 = agg(ys) [split halves for visibility]
    const int HALF = N / 2;   // 50000
    gemm_kernel<128, 64, false, false, true><<<1563, 256, 0, stream>>>(bufP, W3, nullptr, dinv, bufR, N);
    agg64_kernel<<<(HALF + 3) / 4, 256, 0, stream>>>(bufR, row_ptr, col, dinv, bufQ, 0, HALF);
    agg64_kernel<<<(N - HALF + 3) / 4, 256, 0, stream>>>(bufR, row_ptr, col, dinv, bufQ, HALF, N);

    // Pool + MLP head
    pool_kernel<<<(N + POOL_NPB - 1) / POOL_NPB, 256, 0, stream>>>(bufQ, b3, batch, sums, cntf, N);
    mlp_kernel<<<N_GRAPHS, 64, 0, stream>>>(sums, cntf, Wl1, bl1, Wl2, bl2, out);
}

// Round 20
// 506.646 us; speedup vs baseline: 1.1633x; 1.0015x over previous
//
#include <hip/hip_runtime.h>
#include <hip/hip_bf16.h>

#define N_NODES 100000
#define N_EDGES 3200000
#define N_GRAPHS 256
#define NB_BUCKETS 196      // ceil(100000 / 512)
#define BSHIFT 9            // 512 nodes per bucket
#define NBLK 256            // blocks for hist/bin passes
#define SCAN_BLKS 49        // 50176 / 1024
#define CSR_CAP 22528       // LDS staging capacity (88 KB); avg bucket 16.4K edges

// ---------------- workspace layout (bytes) ----------------
#define OFF_SUMS      0u            // float[256*64] pool sums (zeroed in hist)
#define OFF_CNTF      65536u        // float[256] pool counts (zeroed in hist)
#define ZERO_BYTES    66560u
#define OFF_HIST      66560u        // int[196*256] (bucket-major) per-(bucket,block) counts
#define OFF_BSUM      267264u       // int[64] scan block sums
#define OFF_ROWPTR    267776u       // int[N+1]
#define OFF_DINV      668160u       // float[N]
#define OFF_COL       1068544u      // int[E]
#define OFF_XS1       13868544u     // float[N*8]
#define OFF_BUFQ      20268544u     // float[N*64]  xs2, later z3
#define OFF_BUFR      45868544u     // float[N*64]  z2, later ys
#define OFF_BUFP      71468544u     // float[N*128] h2; ALIASED: packed[E] (dead before h2)
#define OFF_PAIRS     OFF_BUFP
// total ~122.7 MB (proven through R19)

// ---- P1: per-(bucket,block) histogram of dst. Also zeroes the pool
// accumulators (was a separate zero_kernel dispatch).
__global__ __launch_bounds__(256) void hist_kernel(const int* __restrict__ dst,
                                                   int* __restrict__ hist,
                                                   int* __restrict__ zbase,
                                                   int E, int epb) {
    __shared__ int h[NB_BUCKETS];
    int t = threadIdx.x, blk = blockIdx.x;
    int gid = blk * 256 + t;
    if (gid < (int)(ZERO_BYTES / 4)) zbase[gid] = 0;
    if (t < NB_BUCKETS) h[t] = 0;
    __syncthreads();
    int e0 = blk * epb, e1 = min(e0 + epb, E);
    for (int e = e0 + t; e < e1; e += 256)
        atomicAdd(&h[__builtin_nontemporal_load(&dst[e]) >> BSHIFT], 1);
    __syncthreads();
    if (t < NB_BUCKETS) hist[t * NBLK + blk] = h[t];
}

// ---- P2: block-local exclusive scan of hist[50176] + per-block sums.
__global__ __launch_bounds__(1024) void scanhA_kernel(int* __restrict__ hist,
                                                      int* __restrict__ bsum) {
    __shared__ int s[1024];
    int t = threadIdx.x;
    int i = blockIdx.x * 1024 + t;     // 49*1024 == 50176 exactly
    int v = hist[i];
    s[t] = v;
    __syncthreads();
    for (int off = 1; off < 1024; off <<= 1) {
        int add = (t >= off) ? s[t - off] : 0;
        __syncthreads();
        s[t] += add;
        __syncthreads();
    }
    hist[i] = s[t] - v;                // block-local exclusive
    if (t == 1023) bsum[blockIdx.x] = s[t];
}

// ---- P3: bin edges, PACKED (dl<<17 | src), local offset scan.
__global__ __launch_bounds__(256) void bin_kernel(const int* __restrict__ src,
                                                  const int* __restrict__ dst,
                                                  const int* __restrict__ hist,
                                                  const int* __restrict__ bsum,
                                                  int* __restrict__ packed, int E, int epb) {
    __shared__ int cur[NB_BUCKETS];
    __shared__ int boffL[SCAN_BLKS];
    int t = threadIdx.x, blk = blockIdx.x;
    if (t < 64) {
        int orig = (t < SCAN_BLKS) ? bsum[t] : 0;
        int v = orig;
        for (int off = 1; off < 64; off <<= 1) {
            int up = __shfl_up(v, off);
            if (t >= off) v += up;
        }
        if (t < SCAN_BLKS) boffL[t] = v - orig;   // exclusive
    }
    __syncthreads();
    if (t < NB_BUCKETS) {
        int i = t * NBLK + blk;
        cur[t] = hist[i] + boffL[i >> 10];
    }
    __syncthreads();
    int e0 = blk * epb, e1 = min(e0 + epb, E);
    for (int e = e0 + t; e < e1; e += 256) {
        int d = __builtin_nontemporal_load(&dst[e]);
        int sv = __builtin_nontemporal_load(&src[e]);
        int pos = atomicAdd(&cur[d >> BSHIFT], 1);
        packed[pos] = ((d & 511) << 17) | sv;
    }
}

// ---- P4: per-bucket CSR finalize + xs1 = dinv*x.
// col scatter STAGED IN LDS (88 KB): bucket output is a contiguous
// permutation -> build in LDS, stream out coalesced. Overflow (>CSR_CAP,
// ~13 sigma) falls back to direct stores.
__global__ __launch_bounds__(512) void csr_kernel(const int* __restrict__ packed,
                                                  const int* __restrict__ hist,
                                                  const int* __restrict__ bsum,
                                                  const float* __restrict__ x,
                                                  int* __restrict__ row_ptr,
                                                  float* __restrict__ dinv,
                                                  float* __restrict__ xs1,
                                                  int* __restrict__ col, int E) {
    __shared__ int cntL[512];
    __shared__ int rsL[512];
    __shared__ int fillL[512];
    __shared__ int boffL[SCAN_BLKS];
    __shared__ int srcL[CSR_CAP];   // 88 KB staging
    int t = threadIdx.x, b = blockIdx.x;
    int lo = b << BSHIFT;
    int nloc = min(512, N_NODES - lo);
    cntL[t] = 0;
    fillL[t] = 0;
    if (t < 64) {
        int orig = (t < SCAN_BLKS) ? bsum[t] : 0;
        int v = orig;
        for (int off = 1; off < 64; off <<= 1) {
            int up = __shfl_up(v, off);
            if (t >= off) v += up;
        }
        if (t < SCAN_BLKS) boffL[t] = v - orig;   // exclusive
    }
    __syncthreads();
    int i0 = b * NBLK;
    int start = hist[i0] + boffL[i0 >> 10];
    int end;
    if (b == NB_BUCKETS - 1) end = E;
    else {
        int i1 = (b + 1) * NBLK;
        end = hist[i1] + boffL[i1 >> 10];
    }
    for (int e = start + t; e < end; e += 512)
        atomicAdd(&cntL[packed[e] >> 17], 1);
    __syncthreads();
    int v = cntL[t];
    __syncthreads();
    for (int off = 1; off < 512; off <<= 1) {     // inclusive scan (Hillis-Steele)
        int add = (t >= off) ? cntL[t - off] : 0;
        __syncthreads();
        cntL[t] += add;
        __syncthreads();
    }
    int rowstart = start + cntL[t] - v;           // exclusive + bucket base
    rsL[t] = rowstart;
    if (t < nloc) {
        int node = lo + t;
        row_ptr[node] = rowstart;
        float d = rsqrtf((float)(v + 1));
        dinv[node] = d;
        const float4* xv = reinterpret_cast<const float4*>(x) + node * 2;
        float4 xa = xv[0], xb = xv[1];
        xa.x *= d; xa.y *= d; xa.z *= d; xa.w *= d;
        xb.x *= d; xb.y *= d; xb.z *= d; xb.w *= d;
        float4* xo = reinterpret_cast<float4*>(xs1) + node * 2;
        xo[0] = xa; xo[1] = xb;
    }
    if (b == NB_BUCKETS - 1 && t == 0) row_ptr[N_NODES] = E;
    __syncthreads();
    for (int e = start + t; e < end; e += 512) {
        int p = packed[e];
        int dl = p >> 17;
        int pos = rsL[dl] + atomicAdd(&fillL[dl], 1);
        int rel = pos - start;
        if (rel < CSR_CAP) srcL[rel] = p & 0x1FFFF;
        else col[pos] = p & 0x1FFFF;          // overflow fallback
    }
    __syncthreads();
    int lim = min(end - start, CSR_CAP);
    for (int i = t; i < lim; i += 512)
        col[start + i] = srcL[i];             // coalesced write-out
}

// Layer-1 aggregation FUSED with gemm1 (proven R13 form).
__global__ __launch_bounds__(256) void agg8g1_kernel(
        const float* __restrict__ xs, const int* __restrict__ row_ptr,
        const int* __restrict__ col, const float* __restrict__ dinv,
        const float* __restrict__ W1, const float* __restrict__ b1,
        float* __restrict__ xs2, int n) {
    int wave = threadIdx.x >> 6;            // 4 waves/block = 4 nodes/block
    int node = blockIdx.x * 4 + wave;
    if (node >= n) return;
    int lane = threadIdx.x & 63;
    int j = lane >> 1, l = lane & 1;
    int e0 = row_ptr[node], e1 = row_ptr[node + 1];
    float4 acc0 = {0.f, 0.f, 0.f, 0.f}, acc1 = acc0;
    if (j == 0) {   // self-loop term, counted once (2 lanes, one per half)
        const float4 sv = *reinterpret_cast<const float4*>(&xs[node * 8 + 4 * l]);
        acc0.x += sv.x; acc0.y += sv.y; acc0.z += sv.z; acc0.w += sv.w;
    }
    int base = e0;
    for (; base + 64 <= e1; base += 64) {   // 64 edges per iteration
        int s0 = __builtin_nontemporal_load(&col[base + j]);
        int s1 = __builtin_nontemporal_load(&col[base + 32 + j]);
        const float4 v0 = *reinterpret_cast<const float4*>(&xs[s0 * 8 + 4 * l]);
        const float4 v1 = *reinterpret_cast<const float4*>(&xs[s1 * 8 + 4 * l]);
        acc0.x += v0.x; acc0.y += v0.y; acc0.z += v0.z; acc0.w += v0.w;
        acc1.x += v1.x; acc1.y += v1.y; acc1.z += v1.z; acc1.w += v1.w;
    }
    if (base < e1) {                        // single masked pass (<=63 edges)
        int ee0 = base + j;
        int ee1 = base + 32 + j;
        int s0 = __builtin_nontemporal_load(&col[min(ee0, e1 - 1)]);
        int s1 = __builtin_nontemporal_load(&col[min(ee1, e1 - 1)]);
        float m0 = (ee0 < e1) ? 1.0f : 0.0f;
        float m1 = (ee1 < e1) ? 1.0f : 0.0f;
        const float4 v0 = *reinterpret_cast<const float4*>(&xs[s0 * 8 + 4 * l]);
        const float4 v1 = *reinterpret_cast<const float4*>(&xs[s1 * 8 + 4 * l]);
        acc0.x += m0 * v0.x; acc0.y += m0 * v0.y; acc0.z += m0 * v0.z; acc0.w += m0 * v0.w;
        acc1.x += m1 * v1.x; acc1.y += m1 * v1.y; acc1.z += m1 * v1.z; acc1.w += m1 * v1.w;
    }
    float4 r;
    r.x = acc0.x + acc1.x; r.y = acc0.y + acc1.y;
    r.z = acc0.z + acc1.z; r.w = acc0.w + acc1.w;
    r.x += __shfl_xor(r.x, 2);  r.y += __shfl_xor(r.y, 2);
    r.z += __shfl_xor(r.z, 2);  r.w += __shfl_xor(r.w, 2);
    r.x += __shfl_xor(r.x, 4);  r.y += __shfl_xor(r.y, 4);
    r.z += __shfl_xor(r.z, 4);  r.w += __shfl_xor(r.w, 4);
    r.x += __shfl_xor(r.x, 8);  r.y += __shfl_xor(r.y, 8);
    r.z += __shfl_xor(r.z, 8);  r.w += __shfl_xor(r.w, 8);
    r.x += __shfl_xor(r.x, 16); r.y += __shfl_xor(r.y, 16);
    r.z += __shfl_xor(r.z, 16); r.w += __shfl_xor(r.w, 16);
    r.x += __shfl_xor(r.x, 32); r.y += __shfl_xor(r.y, 32);
    r.z += __shfl_xor(r.z, 32); r.w += __shfl_xor(r.w, 32);
    float d = dinv[node];
    r.x *= d; r.y *= d; r.z *= d; r.w *= d;
    float z10 = __shfl(r.x, 0), z11 = __shfl(r.y, 0);
    float z12 = __shfl(r.z, 0), z13 = __shfl(r.w, 0);
    float z14 = __shfl(r.x, 1), z15 = __shfl(r.y, 1);
    float z16 = __shfl(r.z, 1), z17 = __shfl(r.w, 1);
    float a = b1[lane];
    a += z10 * W1[0 * 64 + lane];
    a += z11 * W1[1 * 64 + lane];
    a += z12 * W1[2 * 64 + lane];
    a += z13 * W1[3 * 64 + lane];
    a += z14 * W1[4 * 64 + lane];
    a += z15 * W1[5 * 64 + lane];
    a += z16 * W1[6 * 64 + lane];
    a += z17 * W1[7 * 64 + lane];
    xs2[node * 64 + lane] = d * fmaxf(a, 0.0f);
}

// D=64 aggregation, float4-per-lane gather, batched masked remainder
// (proven form; both layer calls merged -- visibility split retired).
__global__ __launch_bounds__(256) void agg64_kernel(
        const float* __restrict__ xs, const int* __restrict__ row_ptr,
        const int* __restrict__ col, const float* __restrict__ dinv,
        float* __restrict__ z, int n) {
    int wave = threadIdx.x >> 6;            // 4 waves/block = 4 nodes/block
    int node = blockIdx.x * 4 + wave;
    if (node >= n) return;
    int lane = threadIdx.x & 63;
    int j = lane >> 4, l = lane & 15;
    int e0 = row_ptr[node], e1 = row_ptr[node + 1];
    float4 acc0 = {0.f, 0.f, 0.f, 0.f}, acc1 = acc0, acc2 = acc0, acc3 = acc0;
    if (j == 0) {   // self-loop term, counted once
        const float4 sv = *reinterpret_cast<const float4*>(&xs[node * 64 + 4 * l]);
        acc0.x += sv.x; acc0.y += sv.y; acc0.z += sv.z; acc0.w += sv.w;
    }
    int base = e0;
    for (; base + 32 <= e1; base += 32) {   // 32 edges per iteration
        int s0 = __builtin_nontemporal_load(&col[base + j]);
        int s1 = __builtin_nontemporal_load(&col[base + 4 + j]);
        int s2 = __builtin_nontemporal_load(&col[base + 8 + j]);
        int s3 = __builtin_nontemporal_load(&col[base + 12 + j]);
        int s4 = __builtin_nontemporal_load(&col[base + 16 + j]);
        int s5 = __builtin_nontemporal_load(&col[base + 20 + j]);
        int s6 = __builtin_nontemporal_load(&col[base + 24 + j]);
        int s7 = __builtin_nontemporal_load(&col[base + 28 + j]);
        const float4 v0 = *reinterpret_cast<const float4*>(&xs[s0 * 64 + 4 * l]);
        const float4 v1 = *reinterpret_cast<const float4*>(&xs[s1 * 64 + 4 * l]);
        const float4 v2 = *reinterpret_cast<const float4*>(&xs[s2 * 64 + 4 * l]);
        const float4 v3 = *reinterpret_cast<const float4*>(&xs[s3 * 64 + 4 * l]);
        const float4 v4 = *reinterpret_cast<const float4*>(&xs[s4 * 64 + 4 * l]);
        const float4 v5 = *reinterpret_cast<const float4*>(&xs[s5 * 64 + 4 * l]);
        const float4 v6 = *reinterpret_cast<const float4*>(&xs[s6 * 64 + 4 * l]);
        const float4 v7 = *reinterpret_cast<const float4*>(&xs[s7 * 64 + 4 * l]);
        acc0.x += v0.x; acc0.y += v0.y; acc0.z += v0.z; acc0.w += v0.w;
        acc1.x += v1.x; acc1.y += v1.y; acc1.z += v1.z; acc1.w += v1.w;
        acc2.x += v2.x; acc2.y += v2.y; acc2.z += v2.z; acc2.w += v2.w;
        acc3.x += v3.x; acc3.y += v3.y; acc3.z += v3.z; acc3.w += v3.w;
        acc0.x += v4.x; acc0.y += v4.y; acc0.z += v4.z; acc0.w += v4.w;
        acc1.x += v5.x; acc1.y += v5.y; acc1.z += v5.z; acc1.w += v5.w;
        acc2.x += v6.x; acc2.y += v6.y; acc2.z += v6.z; acc2.w += v6.w;
        acc3.x += v7.x; acc3.y += v7.y; acc3.z += v7.z; acc3.w += v7.w;
    }
    if (base < e1) {   // single masked pass for <=31 remaining edges
        int ee0 = base + j,      ee1 = base + 4 + j;
        int ee2 = base + 8 + j,  ee3 = base + 12 + j;
        int ee4 = base + 16 + j, ee5 = base + 20 + j;
        int ee6 = base + 24 + j, ee7 = base + 28 + j;
        int s0 = __builtin_nontemporal_load(&col[min(ee0, e1 - 1)]);
        int s1 = __builtin_nontemporal_load(&col[min(ee1, e1 - 1)]);
        int s2 = __builtin_nontemporal_load(&col[min(ee2, e1 - 1)]);
        int s3 = __builtin_nontemporal_load(&col[min(ee3, e1 - 1)]);
        int s4 = __builtin_nontemporal_load(&col[min(ee4, e1 - 1)]);
        int s5 = __builtin_nontemporal_load(&col[min(ee5, e1 - 1)]);
        int s6 = __builtin_nontemporal_load(&col[min(ee6, e1 - 1)]);
        int s7 = __builtin_nontemporal_load(&col[min(ee7, e1 - 1)]);
        float m0 = (ee0 < e1) ? 1.f : 0.f, m1 = (ee1 < e1) ? 1.f : 0.f;
        float m2 = (ee2 < e1) ? 1.f : 0.f, m3 = (ee3 < e1) ? 1.f : 0.f;
        float m4 = (ee4 < e1) ? 1.f : 0.f, m5 = (ee5 < e1) ? 1.f : 0.f;
        float m6 = (ee6 < e1) ? 1.f : 0.f, m7 = (ee7 < e1) ? 1.f : 0.f;
        const float4 v0 = *reinterpret_cast<const float4*>(&xs[s0 * 64 + 4 * l]);
        const float4 v1 = *reinterpret_cast<const float4*>(&xs[s1 * 64 + 4 * l]);
        const float4 v2 = *reinterpret_cast<const float4*>(&xs[s2 * 64 + 4 * l]);
        const float4 v3 = *reinterpret_cast<const float4*>(&xs[s3 * 64 + 4 * l]);
        const float4 v4 = *reinterpret_cast<const float4*>(&xs[s4 * 64 + 4 * l]);
        const float4 v5 = *reinterpret_cast<const float4*>(&xs[s5 * 64 + 4 * l]);
        const float4 v6 = *reinterpret_cast<const float4*>(&xs[s6 * 64 + 4 * l]);
        const float4 v7 = *reinterpret_cast<const float4*>(&xs[s7 * 64 + 4 * l]);
        acc0.x += m0 * v0.x; acc0.y += m0 * v0.y; acc0.z += m0 * v0.z; acc0.w += m0 * v0.w;
        acc1.x += m1 * v1.x; acc1.y += m1 * v1.y; acc1.z += m1 * v1.z; acc1.w += m1 * v1.w;
        acc2.x += m2 * v2.x; acc2.y += m2 * v2.y; acc2.z += m2 * v2.z; acc2.w += m2 * v2.w;
        acc3.x += m3 * v3.x; acc3.y += m3 * v3.y; acc3.z += m3 * v3.z; acc3.w += m3 * v3.w;
        acc0.x += m4 * v4.x; acc0.y += m4 * v4.y; acc0.z += m4 * v4.z; acc0.w += m4 * v4.w;
        acc1.x += m5 * v5.x; acc1.y += m5 * v5.y; acc1.z += m5 * v5.z; acc1.w += m5 * v5.w;
        acc2.x += m6 * v6.x; acc2.y += m6 * v6.y; acc2.z += m6 * v6.z; acc2.w += m6 * v6.w;
        acc3.x += m7 * v7.x; acc3.y += m7 * v7.y; acc3.z += m7 * v7.z; acc3.w += m7 * v7.w;
    }
    float4 r;
    r.x = (acc0.x + acc1.x) + (acc2.x + acc3.x);
    r.y = (acc0.y + acc1.y) + (acc2.y + acc3.y);
    r.z = (acc0.z + acc1.z) + (acc2.z + acc3.z);
    r.w = (acc0.w + acc1.w) + (acc2.w + acc3.w);
    r.x += __shfl_xor(r.x, 16); r.y += __shfl_xor(r.y, 16);
    r.z += __shfl_xor(r.z, 16); r.w += __shfl_xor(r.w, 16);
    r.x += __shfl_xor(r.x, 32); r.y += __shfl_xor(r.y, 32);
    r.z += __shfl_xor(r.z, 32); r.w += __shfl_xor(r.w, 32);
    if (j == 0) {
        float d = dinv[node];
        r.x *= d; r.y *= d; r.z *= d; r.w *= d;
        *reinterpret_cast<float4*>(&z[node * 64 + 4 * l]) = r;
    }
}

// Y[row, :] = opt_scale(dinv[row]) * opt_relu( X[row,:] @ W + opt_bias )
// Register-blocked 4x4, bounded unroll (R16 proven form).
template <int K, int M, bool BIAS, bool RELU, bool SCALE>
__global__ __launch_bounds__(256) void gemm_kernel(
        const float* __restrict__ X, const float* __restrict__ W,
        const float* __restrict__ b, const float* __restrict__ dinv,
        float* __restrict__ Y, int nrows) {
    constexpr int CG = M / 4;          // col-groups (gemm2: 32, gemm3: 16)
    constexpr int RG = 256 / CG;       // row-groups  (gemm2: 8,  gemm3: 16)
    constexpr int ROWS = RG * 4;       // rows/tile   (gemm2: 32, gemm3: 64)
    constexpr int XSTR = K + 4;        // padded X stride (bank decorrelation)
    __shared__ float Wl[K * M];        // 32 KB
    __shared__ float Xl[ROWS * XSTR];
    __shared__ float Bl[M];
    int tid = threadIdx.x;
    {   // float4 weight staging
        const float4* Wv = reinterpret_cast<const float4*>(W);
        float4* Wlv = reinterpret_cast<float4*>(Wl);
        for (int i = tid; i < K * M / 4; i += 256) Wlv[i] = Wv[i];
    }
    if (tid < M) Bl[tid] = BIAS ? b[tid] : 0.0f;
    int cg = tid % CG;
    int rg = tid / CG;
    int ntiles = (nrows + ROWS - 1) / ROWS;
    for (int tile = blockIdx.x; tile < ntiles; tile += gridDim.x) {
        int row0 = tile * ROWS;
        __syncthreads();
        {   // stage X tile (float4, padded rows, zero-fill tail)
            int base4 = row0 * (K / 4);
            int tot4 = nrows * (K / 4);
            for (int i = tid; i < ROWS * K / 4; i += 256) {
                float4 v = {0.f, 0.f, 0.f, 0.f};
                if (base4 + i < tot4) v = reinterpret_cast<const float4*>(X)[base4 + i];
                int rr = i / (K / 4), kk = i % (K / 4);
                *reinterpret_cast<float4*>(&Xl[rr * XSTR + kk * 4]) = v;
            }
        }
        __syncthreads();
        float4 acc[4];
#pragma unroll
        for (int rr = 0; rr < 4; ++rr)
            acc[rr] = *reinterpret_cast<const float4*>(&Bl[cg * 4]);
#pragma unroll 1
        for (int k = 0; k < K; k += 4) {
            const float4 w0 = *reinterpret_cast<const float4*>(&Wl[(k + 0) * M + cg * 4]);
            const float4 w1 = *reinterpret_cast<const float4*>(&Wl[(k + 1) * M + cg * 4]);
            const float4 w2 = *reinterpret_cast<const float4*>(&Wl[(k + 2) * M + cg * 4]);
            const float4 w3 = *reinterpret_cast<const float4*>(&Wl[(k + 3) * M + cg * 4]);
#pragma unroll
            for (int rr = 0; rr < 4; ++rr) {
                const float4 xv = *reinterpret_cast<const float4*>(
                    &Xl[(rg * 4 + rr) * XSTR + k]);
                acc[rr].x += xv.x * w0.x + xv.y * w1.x + xv.z * w2.x + xv.w * w3.x;
                acc[rr].y += xv.x * w0.y + xv.y * w1.y + xv.z * w2.y + xv.w * w3.y;
                acc[rr].z += xv.x * w0.z + xv.y * w1.z + xv.z * w2.z + xv.w * w3.z;
                acc[rr].w += xv.x * w0.w + xv.y * w1.w + xv.z * w2.w + xv.w * w3.w;
            }
        }
#pragma unroll
        for (int rr = 0; rr < 4; ++rr) {
            int row = row0 + rg * 4 + rr;
            if (row < nrows) {
                float4 a = acc[rr];
                if constexpr (RELU) {
                    a.x = fmaxf(a.x, 0.f); a.y = fmaxf(a.y, 0.f);
                    a.z = fmaxf(a.z, 0.f); a.w = fmaxf(a.w, 0.f);
                }
                if constexpr (SCALE) {
                    float d = dinv[row];
                    a.x *= d; a.y *= d; a.z *= d; a.w *= d;
                }
                *reinterpret_cast<float4*>(&Y[row * M + cg * 4]) = a;
            }
        }
    }
}

// h3 = relu(z3 + b3); pool sums/counts per graph (R18 proven form).
#define POOL_NPB 128   // nodes per block (32 per wave, contiguous)
__global__ __launch_bounds__(256) void pool_kernel(
        const float* __restrict__ z3, const float* __restrict__ b3,
        const int* __restrict__ batch, float* __restrict__ sums,
        float* __restrict__ cntf, int n) {
    int wave = threadIdx.x >> 6;
    int lane = threadIdx.x & 63;   // feature index
    int node0 = blockIdx.x * POOL_NPB + wave * 32;
    int nodeEnd = min(node0 + 32, n);
    if (node0 >= n) return;
    float bias = b3[lane];
    float acc = 0.0f, cnt = 0.0f;
    int curg = -1;
    for (int node = node0; node < nodeEnd; ++node) {
        int g = batch[node];               // wave-uniform (lane = feature)
        if (g != curg) {                   // wave-uniform branch
            if (curg >= 0) {
                atomicAdd(&sums[curg * 64 + lane], acc);
                if (lane == 0) atomicAdd(&cntf[curg], cnt);
            }
            curg = g; acc = 0.0f; cnt = 0.0f;
        }
        acc += fmaxf(__builtin_nontemporal_load(&z3[node * 64 + lane]) + bias, 0.0f);
        cnt += 1.0f;
    }
    if (curg >= 0) {
        atomicAdd(&sums[curg * 64 + lane], acc);
        if (lane == 0) atomicAdd(&cntf[curg], cnt);
    }
}

// per-graph: g = sums/max(cnt,1); hid = relu(g@Wl1+bl1); out = hid@Wl2+bl2
__global__ void mlp_kernel(const float* __restrict__ sums, const float* __restrict__ cntf,
                           const float* __restrict__ Wl1, const float* __restrict__ bl1,
                           const float* __restrict__ Wl2, const float* __restrict__ bl2,
                           float* __restrict__ out) {
    __shared__ float gv[64];
    __shared__ float hid[32];
    int g = blockIdx.x, t = threadIdx.x;
    float denom = fmaxf(cntf[g], 1.0f);
    gv[t] = sums[g * 64 + t] / denom;
    __syncthreads();
    if (t < 32) {
        float a = bl1[t];
#pragma unroll
        for (int k = 0; k < 64; ++k) a += gv[k] * Wl1[k * 32 + t];
        hid[t] = fmaxf(a, 0.0f);
    }
    __syncthreads();
    if (t == 0) {
        float o = bl2[0];
#pragma unroll
        for (int k = 0; k < 32; ++k) o += hid[k] * Wl2[k];
        out[g] = o;
    }
}

extern "C" void kernel_launch(void* const* d_in, const int* in_sizes, int n_in,
                              void* d_out, int out_size, void* d_ws, size_t ws_size,
                              hipStream_t stream) {
    const float* x   = (const float*)d_in[0];
    const int* ei    = (const int*)d_in[1];
    const int* batch = (const int*)d_in[2];
    const float* W1  = (const float*)d_in[3];
    const float* b1  = (const float*)d_in[4];
    const float* W2  = (const float*)d_in[5];
    const float* b2  = (const float*)d_in[6];
    const float* W3  = (const float*)d_in[7];
    const float* b3  = (const float*)d_in[8];
    const float* Wl1 = (const float*)d_in[9];
    const float* bl1 = (const float*)d_in[10];
    const float* Wl2 = (const float*)d_in[11];
    const float* bl2 = (const float*)d_in[12];
    float* out = (float*)d_out;

    const int N = N_NODES;
    const int E = in_sizes[1] / 2;   // 3.2M
    const int* src = ei;
    const int* dst = ei + E;

    char* ws = (char*)d_ws;
    float* sums    = (float*)(ws + OFF_SUMS);
    float* cntf    = (float*)(ws + OFF_CNTF);
    int*   hist    = (int*)(ws + OFF_HIST);
    int*   bsum    = (int*)(ws + OFF_BSUM);
    int*   row_ptr = (int*)(ws + OFF_ROWPTR);
    float* dinv    = (float*)(ws + OFF_DINV);
    int*   col     = (int*)(ws + OFF_COL);
    float* xs1     = (float*)(ws + OFF_XS1);
    float* bufQ    = (float*)(ws + OFF_BUFQ);   // xs2, later z3
    float* bufR    = (float*)(ws + OFF_BUFR);   // z2, later ys
    float* bufP    = (float*)(ws + OFF_BUFP);   // h2
    int*   packed  = (int*)(ws + OFF_PAIRS);    // aliases bufP (dead before h2)

    // CSR build: hist(+zero) -> scanA -> bin -> csr(+xs1 scale, LDS-staged col)
    int epb = (E + NBLK - 1) / NBLK;   // 12500
    hist_kernel<<<NBLK, 256, 0, stream>>>(dst, hist, (int*)ws, E, epb);
    scanhA_kernel<<<SCAN_BLKS, 1024, 0, stream>>>(hist, bsum);
    bin_kernel<<<NBLK, 256, 0, stream>>>(src, dst, hist, bsum, packed, E, epb);
    csr_kernel<<<NB_BUCKETS, 512, 0, stream>>>(packed, hist, bsum, x,
                                               row_ptr, dinv, xs1, col, E);

    // Layer 1 (agg + gemm1 fused): xs2 = dinv*relu((agg xs1)@W1+b1)
    agg8g1_kernel<<<(N + 3) / 4, 256, 0, stream>>>(xs1, row_ptr, col, dinv, W1, b1, bufQ, N);

    // Layer 2: z2 = agg(xs2) ; h2 = relu(z2@W2+b2)
    agg64_kernel<<<(N + 3) / 4, 256, 0, stream>>>(bufQ, row_ptr, col, dinv, bufR, N);
    gemm_kernel<64, 128, true, true, false><<<3125, 256, 0, stream>>>(bufR, W2, b2, nullptr, bufP, N);

    // Layer 3: ys = dinv*(h2@W3) ; z3 = agg(ys)
    gemm_kernel<128, 64, false, false, true><<<1563, 256, 0, stream>>>(bufP, W3, nullptr, dinv, bufR, N);
    agg64_kernel<<<(N + 3) / 4, 256, 0, stream>>>(bufR, row_ptr, col, dinv, bufQ, N);

    // Pool + MLP head
    pool_kernel<<<(N + POOL_NPB - 1) / POOL_NPB, 256, 0, stream>>>(bufQ, b3, batch, sums, cntf, N);
    mlp_kernel<<<N_GRAPHS, 64, 0, stream>>>(sums, cntf, Wl1, bl1, Wl2, bl2, out);
}